// Round 16
// baseline (1543.989 us; speedup 1.0000x reference)
//
#include <hip/hip_runtime.h>
#include <hip/hip_bf16.h>

// ---------------------------------------------------------------------------
#define SEQ   100
#define BATCH 32
#define FLATIN 15873
#define KPAD1  16384
#define ROWS   3200
#define MPAD   3328
#define NOUT3  16000

typedef __attribute__((ext_vector_type(8))) short short8;
typedef __attribute__((ext_vector_type(4))) short short4v;
typedef __attribute__((ext_vector_type(4))) float f32x4;
typedef __hip_bfloat16 bf16;

__device__ __forceinline__ void gload_lds16(const void* g, void* l) {
  __builtin_amdgcn_global_load_lds((const __attribute__((address_space(1))) void*)g,
                                   (__attribute__((address_space(3))) void*)l, 16, 0, 0);
}

// bijective XCD chunk swizzle (m204)
__device__ __forceinline__ int xcd_swizzle(int id, int nwg) {
  const int q = nwg >> 3, r = nwg & 7;
  const int x = id & 7, p = id >> 3;
  return (x < r ? x * (q + 1) : r * (q + 1) + (x - r) * q) + p;
}

// ---------------------------------------------------------------------------
// Shared GEMM body: stage 128x64 A/B tiles (both-sides chunk swizzle), MFMA.
#define GEMM_BODY(KBEG, KEND)                                                   \
  const int tid  = threadIdx.x;                                                 \
  const int lane = tid & 63;                                                    \
  const int wid  = tid >> 6;                                                    \
  const int wr = (wid >> 1) << 6;                                               \
  const int wc = (wid & 1) << 6;                                                \
  f32x4 acc[4][4];                                                              \
  _Pragma("unroll") for (int i = 0; i < 4; ++i)                                 \
  _Pragma("unroll") for (int j = 0; j < 4; ++j)                                 \
      acc[i][j] = (f32x4){0.f, 0.f, 0.f, 0.f};                                  \
  const int srow = (wid << 3) + (lane >> 3);                                    \
  const int scs  = lane & 7;                                                    \
  const int gcol = ((scs ^ (srow & 7)) << 3);                                   \
  const bf16* arow[4];                                                          \
  const bf16* brow[4];                                                          \
  _Pragma("unroll") for (int j = 0; j < 4; ++j) {                               \
    const int row = (j << 5) + srow;                                            \
    const int gr = GATHER ? idx[m0 + row] : (m0 + row);                         \
    arow[j] = A + (size_t)gr * K + gcol;                                        \
    brow[j] = W + (size_t)(n0 + row) * K + gcol;                                \
  }                                                                             \
  for (int k0 = (KBEG); k0 < (KEND); k0 += 64) {                                \
    __syncthreads();                                                            \
    _Pragma("unroll") for (int j = 0; j < 4; ++j) {                             \
      short* la = As + (((j << 2) + wid) << 9);                                 \
      short* lb = Bs + (((j << 2) + wid) << 9);                                 \
      gload_lds16(arow[j] + k0, la);                                            \
      gload_lds16(brow[j] + k0, lb);                                            \
    }                                                                           \
    __syncthreads();                                                            \
    _Pragma("unroll") for (int kk = 0; kk < 2; ++kk) {                          \
      short8 af[4], bfv[4];                                                     \
      _Pragma("unroll") for (int i = 0; i < 4; ++i) {                           \
        const int mr = wr + (i << 4) + (lane & 15);                             \
        const int cg = (kk << 2) + (lane >> 4);                                 \
        af[i]  = *(const short8*)(As + mr * 64 + ((cg ^ (mr & 7)) << 3));       \
        const int nr = wc + (i << 4) + (lane & 15);                             \
        bfv[i] = *(const short8*)(Bs + nr * 64 + ((cg ^ (nr & 7)) << 3));       \
      }                                                                         \
      _Pragma("unroll") for (int i = 0; i < 4; ++i)                             \
      _Pragma("unroll") for (int j = 0; j < 4; ++j)                             \
          acc[i][j] = __builtin_amdgcn_mfma_f32_16x16x32_bf16(af[i], bfv[j],    \
                                                              acc[i][j], 0,0,0);\
    }                                                                           \
  }

// Split-K partial-output GEMM. mt-minor linearization.
template<int GATHER>
__global__ __launch_bounds__(256)
void gemm_bf16(const bf16* __restrict__ A, const bf16* __restrict__ W,
               const int* __restrict__ idx, const int* __restrict__ cnt,
               float* __restrict__ P,
               int K, int ldc, int mtiles, int ksl, size_t pstride)
{
  __shared__ __align__(16) short lds[16384];
  short* As = lds;
  short* Bs = lds + 8192;
  const int wg = xcd_swizzle(blockIdx.x, gridDim.x);
  const int mt = wg % mtiles;
  const int g  = wg / mtiles;
  const int nt = g / ksl;
  const int ks = g % ksl;
  const int m0 = mt << 7;
  const int n0 = nt << 7;
  if (cnt && m0 >= cnt[0]) return;
  const int Klen = K / ksl;
  const int kbeg = ks * Klen;

  GEMM_BODY(kbeg, kbeg + Klen)

  float* Pout = P + (size_t)ks * pstride;
  const int fr = lane & 15, fq = lane >> 4;
#pragma unroll
  for (int j = 0; j < 4; ++j) {
    const int n = n0 + wc + (j << 4) + fr;
#pragma unroll
    for (int i = 0; i < 4; ++i)
#pragma unroll
      for (int r = 0; r < 4; ++r) {
        const int m = m0 + wr + (i << 4) + (fq << 2) + r;
        Pout[(size_t)m * ldc + n] = acc[i][j][r];
      }
  }
}

// Direct GEMM with fused bias/relu epilogue
template<int RELU, int OF32, int OB16>
__global__ __launch_bounds__(256)
void gemm_direct(const bf16* __restrict__ A, const bf16* __restrict__ W,
                 const float* __restrict__ bias, float* __restrict__ Cf,
                 bf16* __restrict__ Cb, int K, int ldc, int mtiles)
{
  __shared__ __align__(16) short lds[16384];
  short* As = lds;
  short* Bs = lds + 8192;
  const int GATHER = 0;
  const int* idx = nullptr;
  const int wg = xcd_swizzle(blockIdx.x, gridDim.x);
  const int m0 = (wg % mtiles) << 7;
  const int n0 = (wg / mtiles) << 7;

  GEMM_BODY(0, K)

  const int fr = lane & 15, fq = lane >> 4;
#pragma unroll
  for (int j = 0; j < 4; ++j) {
    const int n = n0 + wc + (j << 4) + fr;
    const float bb = bias[n];
#pragma unroll
    for (int i = 0; i < 4; ++i)
#pragma unroll
      for (int r = 0; r < 4; ++r) {
        const int m = m0 + wr + (i << 4) + (fq << 2) + r;
        float v = acc[i][j][r] + bb;
        if (RELU) v = fmaxf(v, 0.f);
        if (OF32) Cf[(size_t)m * ldc + n] = v;
        if (OB16) Cb[(size_t)m * ldc + n] = __float2bfloat16(v);
      }
  }
}

// ---------------------------------------------------------------------------
// Split-K GEMM with fp32 B-side (conversion fused into staging; rule #21:
// inverse-swizzled write + swizzled read). B rows clamped to wrows-1.
__global__ __launch_bounds__(256)
void gemm_w32(const bf16* __restrict__ A, const float* __restrict__ W32,
              float* __restrict__ P, int K, int ldc, int ksl, size_t pstride,
              int wrows)
{
  __shared__ __align__(16) short lds[16384];
  short* As = lds;
  short* Bs = lds + 8192;
  const int wg = xcd_swizzle(blockIdx.x, gridDim.x);
  const int nt = wg / ksl;
  const int ks = wg % ksl;
  const int m0 = 0;
  const int n0 = nt << 7;
  const int Klen = K / ksl;
  const int kbeg = ks * Klen;
  const int kend = kbeg + Klen;

  const int tid  = threadIdx.x;
  const int lane = tid & 63;
  const int wid  = tid >> 6;
  const int wr = (wid >> 1) << 6;
  const int wc = (wid & 1) << 6;

  f32x4 acc[4][4];
#pragma unroll
  for (int i = 0; i < 4; ++i)
#pragma unroll
    for (int j = 0; j < 4; ++j) acc[i][j] = (f32x4){0.f, 0.f, 0.f, 0.f};

  const int srow = (wid << 3) + (lane >> 3);
  const int scs  = lane & 7;
  const int gcol = ((scs ^ (srow & 7)) << 3);

  const bf16* arow[4];
#pragma unroll
  for (int j = 0; j < 4; ++j)
    arow[j] = A + (size_t)(m0 + (j << 5) + srow) * K + gcol;

  const float* wsrc[4];
  int bslot[4];
#pragma unroll
  for (int i = 0; i < 4; ++i) {
    const int q = (i << 8) + tid;
    const int row = q >> 3, c = q & 7;
    const int wrow = min(n0 + row, wrows - 1);
    wsrc[i] = W32 + (size_t)wrow * K + (c << 3);
    bslot[i] = row * 64 + ((c ^ (row & 7)) << 3);
  }

  for (int k0 = kbeg; k0 < kend; k0 += 64) {
    __syncthreads();
#pragma unroll
    for (int j = 0; j < 4; ++j)
      gload_lds16(arow[j] + k0, As + (((j << 2) + wid) << 9));
#pragma unroll
    for (int i = 0; i < 4; ++i) {
      const float4 w0 = *(const float4*)(wsrc[i] + k0);
      const float4 w1 = *(const float4*)(wsrc[i] + k0 + 4);
      union { short8 v; bf16 h[8]; } pk;
      pk.h[0] = __float2bfloat16(w0.x); pk.h[1] = __float2bfloat16(w0.y);
      pk.h[2] = __float2bfloat16(w0.z); pk.h[3] = __float2bfloat16(w0.w);
      pk.h[4] = __float2bfloat16(w1.x); pk.h[5] = __float2bfloat16(w1.y);
      pk.h[6] = __float2bfloat16(w1.z); pk.h[7] = __float2bfloat16(w1.w);
      *(short8*)(Bs + bslot[i]) = pk.v;
    }
    __syncthreads();
#pragma unroll
    for (int kk = 0; kk < 2; ++kk) {
      short8 af[4], bfv[4];
#pragma unroll
      for (int i = 0; i < 4; ++i) {
        const int mr = wr + (i << 4) + (lane & 15);
        const int cg = (kk << 2) + (lane >> 4);
        af[i]  = *(const short8*)(As + mr * 64 + ((cg ^ (mr & 7)) << 3));
        const int nr = wc + (i << 4) + (lane & 15);
        bfv[i] = *(const short8*)(Bs + nr * 64 + ((cg ^ (nr & 7)) << 3));
      }
#pragma unroll
      for (int i = 0; i < 4; ++i)
#pragma unroll
        for (int j = 0; j < 4; ++j)
          acc[i][j] = __builtin_amdgcn_mfma_f32_16x16x32_bf16(af[i], bfv[j], acc[i][j], 0, 0, 0);
    }
  }

  float* Pout = P + (size_t)ks * pstride;
  const int fr = lane & 15, fq = lane >> 4;
#pragma unroll
  for (int j = 0; j < 4; ++j) {
    const int n = n0 + wc + (j << 4) + fr;
#pragma unroll
    for (int i = 0; i < 4; ++i)
#pragma unroll
      for (int r = 0; r < 4; ++r) {
        const int m = m0 + wr + (i << 4) + (fq << 2) + r;
        Pout[(size_t)m * ldc + n] = acc[i][j][r];
      }
  }
}

// ---------------------------------------------------------------------------
// Split-K reduce: C = sum_ks P[ks] + bias [, relu]
template<int RELU, int OF32, int OB16>
__global__ __launch_bounds__(256)
void reduce_kernel(const float* __restrict__ P, size_t pstride, int ksl,
                   const float* __restrict__ bias, float* __restrict__ Cf,
                   bf16* __restrict__ Cb, int N, const int* __restrict__ cnt)
{
  const int row = blockIdx.y;
  if (cnt) { const int cp = (cnt[0] + 127) & ~127; if (row >= cp) return; }
  const int n = (blockIdx.x * 256 + threadIdx.x) * 4;
  if (n >= N) return;
  const size_t o = (size_t)row * N + n;
  const float4 b4 = *(const float4*)(bias + n);
  float4 s = *(const float4*)(P + o);
  for (int k = 1; k < ksl; ++k) {
    const float4 p = *(const float4*)(P + (size_t)k * pstride + o);
    s.x += p.x; s.y += p.y; s.z += p.z; s.w += p.w;
  }
  s.x += b4.x; s.y += b4.y; s.z += b4.z; s.w += b4.w;
  if (RELU) {
    s.x = fmaxf(s.x, 0.f); s.y = fmaxf(s.y, 0.f);
    s.z = fmaxf(s.z, 0.f); s.w = fmaxf(s.w, 0.f);
  }
  if (OF32) *(float4*)(Cf + o) = s;
  if (OB16) {
    union { short4v v; bf16 h[4]; } u;
    u.h[0] = __float2bfloat16(s.x);
    u.h[1] = __float2bfloat16(s.y);
    u.h[2] = __float2bfloat16(s.z);
    u.h[3] = __float2bfloat16(s.w);
    *(short4v*)(Cb + o) = u.v;
  }
}

// Compaction + padding mask + decoder-KV bias concat (single block)
__global__ __launch_bounds__(256)
void compact_kernel(const int* __restrict__ nz, int* __restrict__ idx,
                    int* __restrict__ pos, int* __restrict__ cnt,
                    int* __restrict__ pad,
                    const float* __restrict__ dkvb, float* __restrict__ kvbias)
{
  __shared__ int wsum[4];
  __shared__ int total;
  const int t = threadIdx.x;
  int loc[13];
  int c = 0;
#pragma unroll
  for (int i = 0; i < 13; ++i) {
    const int m = t * 13 + i;
    loc[i] = (m < ROWS) ? nz[m] : 0;
    c += loc[i];
  }
  int v = c;
#pragma unroll
  for (int o = 1; o < 64; o <<= 1) {
    const int u = __shfl_up(v, o);
    if ((t & 63) >= o) v += u;
  }
  if ((t & 63) == 63) wsum[t >> 6] = v;
  __syncthreads();
  int wbase = 0;
  for (int w = 0; w < (t >> 6); ++w) wbase += wsum[w];
  int p = wbase + v - c;
#pragma unroll
  for (int i = 0; i < 13; ++i) {
    const int m = t * 13 + i;
    if (m < ROWS) {
      if (loc[i]) { idx[p] = m; pos[m] = p; ++p; }
      else pos[m] = -1;
    }
  }
  if (t == 255) total = p;
  __syncthreads();
  const int count = total;
  if (t == 0) cnt[0] = count + 1;
  for (int i = count + t; i < MPAD; i += 256) idx[i] = ROWS;
  for (int m = t; m < ROWS; m += 256) if (pos[m] < 0) pos[m] = count;
  if (t < 32) {
    int any = 0;
    for (int s = 99; s >= 0; --s) {
      any |= nz[t * 100 + s];
      pad[t * 100 + s] = (s > 0 && !any) ? 1 : 0;
    }
  }
#pragma unroll
  for (int i = t; i < 2048; i += 256) {
    const int L = i >> 10, j = i & 1023;
    kvbias[i] = dkvb[L * 1536 + 512 + j];
  }
}

// ---------------------------------------------------------------------------
// Merged prep kernel: conv_x | multi-cvt | fc1 padded cvt | multi transpose.
// All partitions data-independent -> blockIdx-partitioned, no inter-phase sync.
struct CvtArgs {
  const float* src[8];
  bf16* dst[8];
  int cum[8];
};
struct TrArgs {
  const float* src[13];
  float* dst[13];
  int R[13], C[13], cum[13];
};
struct PrepArgs {
  CvtArgs cv;
  TrArgs tr;
  const float* x;
  bf16* xb;
  int* nz;
  const float* fc1w;
  bf16* wb1;
  int nConv, nCvt, nFc1;   // block counts of first three partitions
};
__global__ __launch_bounds__(256)
void prep_kernel(PrepArgs a)
{
  __shared__ float tbuf[64][65];
  __shared__ int sred[4];
  const int bid0 = blockIdx.x;
  if (bid0 < a.nConv) {
    // ---- conv_x partition: x -> xb bf16 + nz flag (row = bid0) ----
    const int m = bid0;                    // 0..ROWS
    const int t = threadIdx.x;
    bf16* dst = a.xb + (size_t)m * KPAD1;
    if (m == ROWS) {
      const __hip_bfloat162 z2 = {__float2bfloat16(0.f), __float2bfloat16(0.f)};
      for (int c = t; c < (KPAD1 >> 1); c += 256) *(__hip_bfloat162*)(dst + 2 * c) = z2;
      return;
    }
    const float* src = a.x + (size_t)m * FLATIN;
    int any = 0;
    for (int c = t; c < (KPAD1 >> 1); c += 256) {
      const int c0 = 2 * c;
      const float v0 = (c0 < FLATIN) ? src[c0] : 0.f;
      const float v1 = (c0 + 1 < FLATIN) ? src[c0 + 1] : 0.f;
      any |= (v0 != 0.f) | (v1 != 0.f);
      __hip_bfloat162 pr;
      pr.x = __float2bfloat16(v0);
      pr.y = __float2bfloat16(v1);
      *(__hip_bfloat162*)(dst + c0) = pr;
    }
    any = __any(any) ? 1 : 0;
    if ((t & 63) == 0) sred[t >> 6] = any;
    __syncthreads();
    if (t == 0) a.nz[m] = sred[0] | sred[1] | sred[2] | sred[3];
  } else if (bid0 < a.nConv + a.nCvt) {
    const int bid = bid0 - a.nConv;
    int seg = 0;
#pragma unroll
    for (int i = 1; i < 8; ++i) if (bid >= a.cv.cum[i]) seg = i;
    const size_t e0 = ((size_t)(bid - a.cv.cum[seg]) << 11) + (threadIdx.x << 3);
    const float4 v0 = *(const float4*)(a.cv.src[seg] + e0);
    const float4 v1 = *(const float4*)(a.cv.src[seg] + e0 + 4);
    union { short8 v; bf16 h[8]; } pk;
    pk.h[0] = __float2bfloat16(v0.x); pk.h[1] = __float2bfloat16(v0.y);
    pk.h[2] = __float2bfloat16(v0.z); pk.h[3] = __float2bfloat16(v0.w);
    pk.h[4] = __float2bfloat16(v1.x); pk.h[5] = __float2bfloat16(v1.y);
    pk.h[6] = __float2bfloat16(v1.z); pk.h[7] = __float2bfloat16(v1.w);
    *(short8*)(a.cv.dst[seg] + e0) = pk.v;
  } else if (bid0 < a.nConv + a.nCvt + a.nFc1) {
    const int r = bid0 - a.nConv - a.nCvt;  // 0..4095
    const float* src = a.fc1w + (size_t)r * FLATIN;
    bf16* dst = a.wb1 + (size_t)r * KPAD1;
#pragma unroll
    for (int u = 0; u < KPAD1 / 2048; ++u) {
      const int c0 = u * 2048 + threadIdx.x * 8;
      union { short8 v; bf16 h[8]; } pk;
      if (c0 + 8 <= FLATIN) {
        const float4 p = *(const float4*)(src + c0);
        const float4 q = *(const float4*)(src + c0 + 4);
        pk.h[0] = __float2bfloat16(p.x); pk.h[1] = __float2bfloat16(p.y);
        pk.h[2] = __float2bfloat16(p.z); pk.h[3] = __float2bfloat16(p.w);
        pk.h[4] = __float2bfloat16(q.x); pk.h[5] = __float2bfloat16(q.y);
        pk.h[6] = __float2bfloat16(q.z); pk.h[7] = __float2bfloat16(q.w);
      } else {
#pragma unroll
        for (int i = 0; i < 8; ++i)
          pk.h[i] = __float2bfloat16((c0 + i < FLATIN) ? src[c0 + i] : 0.f);
      }
      *(short8*)(dst + c0) = pk.v;
    }
  } else {
    const int bid = bid0 - a.nConv - a.nCvt - a.nFc1;
    int seg = 0;
#pragma unroll
    for (int i = 1; i < 13; ++i) if (bid >= a.tr.cum[i]) seg = i;
    const int local = bid - a.tr.cum[seg];
    const int R = a.tr.R[seg], C = a.tr.C[seg];
    const int tilesC = C >> 6;
    const int r0 = (local / tilesC) << 6;
    const int c0 = (local % tilesC) << 6;
    const int tx = threadIdx.x & 63, ty = threadIdx.x >> 6;
    const float* s = a.tr.src[seg];
    float* d = a.tr.dst[seg];
#pragma unroll
    for (int i = 0; i < 16; ++i) {
      const int rr = (ty << 4) + i;
      tbuf[rr][tx] = s[(size_t)(r0 + rr) * C + c0 + tx];
    }
    __syncthreads();
#pragma unroll
    for (int i = 0; i < 16; ++i) {
      const int cc = (ty << 4) + i;
      d[(size_t)(c0 + cc) * R + r0 + tx] = tbuf[tx][cc];
    }
  }
}

// fc3 reduce + bias + relu + scatter + inline PE
__global__ __launch_bounds__(256)
void scatter_pe_reduce(const float* __restrict__ P, size_t pstride, int ksl,
                       const int* __restrict__ pos, const float* __restrict__ bias,
                       float* __restrict__ hf, bf16* __restrict__ hb)
{
  const int m = blockIdx.x;
  const int s = m % 100, b = m / 100;
  const int src = pos[m];
  const int t = threadIdx.x;
  const size_t sb = (size_t)src * 512;
  const size_t db = (size_t)(s * 32 + b) * 512;
#pragma unroll
  for (int u = 0; u < 2; ++u) {
    const int d = t + u * 256;
    float v = bias[d];
    for (int k = 0; k < ksl; ++k) v += P[(size_t)k * pstride + sb + d];
    const float div = expf((float)(2 * (d >> 1)) * (-9.210340371976184f / 512.f));
    const float arg = (float)s * div;
    const float pe = (d & 1) ? cosf(arg) : sinf(arg);
    v = fmaxf(v, 0.f) + pe;
    hf[db + d] = v;
    hb[db + d] = __float2bfloat16(v);
  }
}

// ---------------------------------------------------------------------------
// LayerNorm over D=512 (+ optional second, final LN fused)
__global__ __launch_bounds__(256)
void ln_kernel(const float* __restrict__ x, const float* __restrict__ res,
               const float* __restrict__ g, const float* __restrict__ bta,
               const float* __restrict__ gf, const float* __restrict__ bf_,
               int dofinal, float* __restrict__ y, bf16* __restrict__ yb)
{
  __shared__ float rs[4], rss[4];
  const int row = blockIdx.x;
  const int t = threadIdx.x;
  const size_t base = (size_t)row * 512;
  float v0 = x[base + t];
  float v1 = x[base + t + 256];
  if (res) { v0 += res[base + t]; v1 += res[base + t + 256]; }
  float o0, o1;
#pragma unroll
  for (int pass = 0; pass < 2; ++pass) {
    float s = v0 + v1, ss = v0 * v0 + v1 * v1;
#pragma unroll
    for (int o = 32; o > 0; o >>= 1) { s += __shfl_xor(s, o); ss += __shfl_xor(ss, o); }
    if ((t & 63) == 0) { rs[t >> 6] = s; rss[t >> 6] = ss; }
    __syncthreads();
    s = rs[0] + rs[1] + rs[2] + rs[3];
    ss = rss[0] + rss[1] + rss[2] + rss[3];
    __syncthreads();
    const float mean = s * (1.f / 512.f);
    const float var = ss * (1.f / 512.f) - mean * mean;
    const float inv = rsqrtf(var + 1e-5f);
    const float* gg = (pass == 0) ? g : gf;
    const float* bb = (pass == 0) ? bta : bf_;
    o0 = (v0 - mean) * inv * gg[t] + bb[t];
    o1 = (v1 - mean) * inv * gg[t + 256] + bb[t + 256];
    if (pass == 1 || !dofinal) break;
    v0 = o0; v1 = o1;
  }
  if (y) {
    y[base + t] = o0;
    y[base + t + 256] = o1;
  }
  if (yb) {
    yb[base + t] = __float2bfloat16(o0);
    yb[base + t + 256] = __float2bfloat16(o1);
  }
}

// ---------------------------------------------------------------------------
// Encoder self-attention. grid (128 bh, 25 qg): 4 q's per block.
__global__ __launch_bounds__(256)
void enc_attn_kernel(const float* __restrict__ qkv, const int* __restrict__ pad,
                     bf16* __restrict__ ob)
{
  __shared__ float Ks[100][129];
  __shared__ float Qs[128];
  __shared__ float Ps[100];
  __shared__ float red[4];
  const int bh = blockIdx.x;
  const int b = bh >> 2, h = bh & 3;
  const int q0 = blockIdx.y * 4;
  const int t = threadIdx.x;
  for (int i = t; i < 12800; i += 256) {
    const int s = i >> 7, d = i & 127;
    Ks[s][d] = qkv[(size_t)(s * 32 + b) * 1536 + 512 + h * 128 + d];
  }
  const int masked = (t < 100) ? pad[b * 100 + t] : 0;
  const float scale = 0.08838834764831845f;
  for (int qi = 0; qi < 4; ++qi) {
    const int q = q0 + qi;
    __syncthreads();
    if (t < 128) Qs[t] = qkv[(size_t)(q * 32 + b) * 1536 + h * 128 + t];
    __syncthreads();
    float sc = -3e38f;
    if (t < 100) {
      const float* kr = &Ks[t][0];
      float a = 0.f;
#pragma unroll 16
      for (int d = 0; d < 128; ++d) a += Qs[d] * kr[d];
      sc = masked ? -1e9f : (a * scale);
    }
    float mx = sc;
#pragma unroll
    for (int o = 32; o > 0; o >>= 1) mx = fmaxf(mx, __shfl_xor(mx, o));
    if ((t & 63) == 0) red[t >> 6] = mx;
    __syncthreads();
    mx = fmaxf(fmaxf(red[0], red[1]), fmaxf(red[2], red[3]));
    const float e = (t < 100) ? expf(sc - mx) : 0.f;
    float sm = e;
#pragma unroll
    for (int o = 32; o > 0; o >>= 1) sm += __shfl_xor(sm, o);
    __syncthreads();
    if ((t & 63) == 0) red[t >> 6] = sm;
    __syncthreads();
    sm = red[0] + red[1] + red[2] + red[3];
    if (t < 100) Ps[t] = e;
    __syncthreads();
    if (t < 128) {
      float a = 0.f;
      const float* vb = qkv + 1024 + h * 128 + t;
      for (int k = 0; k < 100; ++k) a += Ps[k] * vb[(size_t)(k * 32 + b) * 1536];
      ob[(size_t)(q * 32 + b) * 512 + h * 128 + t] = __float2bfloat16(a / sm);
    }
  }
}

// ---------------------------------------------------------------------------
// Fused decoder (BOTH layers row-local -> one kernel, Ts kept in LDS).
template<int N, int K, int RELU>
__device__ __forceinline__ void gemvT(int tid, const float* S,
                                      const float* __restrict__ WT,
                                      const float* __restrict__ bias,
                                      float* out, float* part)
{
  constexpr int NQ = N / 4;
  constexpr int G = 512 / NQ;
  constexpr int KP = K / G;
  const int p = tid % NQ;
  const int g = tid / NQ;
  const float4* wp = (const float4*)WT;
  float ax = 0.f, ay = 0.f, az = 0.f, aw = 0.f;
  const int kend = g * KP + KP;
#pragma unroll 8
  for (int k = g * KP; k < kend; ++k) {
    const float s = S[k];
    const float4 w = wp[(size_t)k * NQ + p];
    ax += s * w.x; ay += s * w.y; az += s * w.z; aw += s * w.w;
  }
  float4 a4 = {ax, ay, az, aw};
  *(float4*)(part + g * N + 4 * p) = a4;
  __syncthreads();
#pragma unroll
  for (int n = tid; n < N; n += 512) {
    float v = bias[n];
#pragma unroll
    for (int q = 0; q < G; ++q) v += part[q * N + n];
    if (RELU) v = fmaxf(v, 0.f);
    out[n] = v;
  }
  __syncthreads();
}

#define BLOCK_LN512(V, G, B, O)                                                 \
  {                                                                             \
    float s_ = (V), ss_ = (V) * (V);                                            \
    _Pragma("unroll")                                                           \
    for (int o_ = 32; o_ > 0; o_ >>= 1) {                                       \
      s_ += __shfl_xor(s_, o_); ss_ += __shfl_xor(ss_, o_);                     \
    }                                                                           \
    if ((tid & 63) == 0) { red[tid >> 6] = s_; red2[tid >> 6] = ss_; }          \
    __syncthreads();                                                            \
    s_ = 0.f; ss_ = 0.f;                                                        \
    _Pragma("unroll")                                                           \
    for (int w_ = 0; w_ < 8; ++w_) { s_ += red[w_]; ss_ += red2[w_]; }          \
    const float mean_ = s_ * (1.f / 512.f);                                     \
    const float inv_ = rsqrtf(ss_ * (1.f / 512.f) - mean_ * mean_ + 1e-5f);     \
    O = ((V) - mean_) * inv_ * (G)[tid] + (B)[tid];                             \
    __syncthreads();                                                            \
  }

struct DecArgs {
  const float* kv01;                  // [3200][2048]; layer L at col L*1024
  const float* WvT0;  const float* WvT1;
  const float* WpT0;  const float* WpT1;
  const float* WqT0;  const float* WqT1;
  const float* WcpT0; const float* WcpT1;
  const float* W1T0;  const float* W1T1;
  const float* W2T0;  const float* W2T1;
  const float* sa_qkv_b; const float* sa_proj_b;
  const float* ca_qkv_b; const float* ca_proj_b;
  const float* ff1_b;    const float* ff2_b;
  const float* ln1_g; const float* ln1_b;
  const float* ln2_g; const float* ln2_b;
  const float* ln3_g; const float* ln3_b;
  const float* lnf_g; const float* lnf_b;
  const float* Wo1T;  const float* ob1;
  bf16* o1b;
};

__global__ __launch_bounds__(512)
void dec2_layer(DecArgs a)
{
  __shared__ float Ts[512], Bs[512], Cs[512], F1[1024], part[2048];
  __shared__ float Ps[4][104];
  __shared__ float red[8], red2[8];
  const int r = blockIdx.x, tid = threadIdx.x;
  Ts[tid] = 1.0f;                          // trg init
  __syncthreads();

  for (int L = 0; L < 2; ++L) {
    const float* WvT  = L ? a.WvT1  : a.WvT0;
    const float* WpT  = L ? a.WpT1  : a.WpT0;
    const float* WqT  = L ? a.WqT1  : a.WqT0;
    const float* WcpT = L ? a.WcpT1 : a.WcpT0;
    const float* W1T  = L ? a.W1T1  : a.W1T0;
    const float* W2T  = L ? a.W2T1  : a.W2T0;
    const float* kvb  = a.kv01 + (size_t)L * 1024;
    const int kvstride = 2048;

    // self-attn (Sq=1: softmax over one key == 1 -> out = V(t))
    gemvT<512, 512, 0>(tid, Ts, WvT, a.sa_qkv_b + L * 1536 + 1024, Bs, part);
    gemvT<512, 512, 0>(tid, Bs, WpT, a.sa_proj_b + L * 512, Cs, part);
    {
      const float rv = Cs[tid] + Ts[tid];
      float o;
      BLOCK_LN512(rv, a.ln1_g + L * 512, a.ln1_b + L * 512, o)
      Ts[tid] = o;                         // t1
    }
    __syncthreads();

    // cross-attn Q
    gemvT<512, 512, 0>(tid, Ts, WqT, a.ca_qkv_b + L * 1536, Bs, part);

    // cross-attention: wave h<4 handles head h; 100 keys, 2 per lane
    if (tid < 256) {
      const int h = tid >> 6, lane = tid & 63;
      const float scale = 0.08838834764831845f;
      const float* Qh = Bs + h * 128;
      float s0, s1 = -3e38f;
      {
        const float* kr = kvb + (size_t)(lane * 32 + r) * kvstride + h * 128;
        float acc = 0.f;
#pragma unroll 16
        for (int d = 0; d < 128; ++d) acc += Qh[d] * kr[d];
        s0 = acc * scale;
      }
      if (lane + 64 < 100) {
        const float* kr = kvb + (size_t)((lane + 64) * 32 + r) * kvstride + h * 128;
        float acc = 0.f;
#pragma unroll 16
        for (int d = 0; d < 128; ++d) acc += Qh[d] * kr[d];
        s1 = acc * scale;
      }
      float mx = fmaxf(s0, s1);
#pragma unroll
      for (int o = 32; o > 0; o >>= 1) mx = fmaxf(mx, __shfl_xor(mx, o));
      const float e0 = expf(s0 - mx);
      const float e1 = (lane + 64 < 100) ? expf(s1 - mx) : 0.f;
      float sm = e0 + e1;
#pragma unroll
      for (int o = 32; o > 0; o >>= 1) sm += __shfl_xor(sm, o);
      Ps[h][lane] = e0 / sm;
      if (lane + 64 < 100) Ps[h][lane + 64] = e1 / sm;
    }
    __syncthreads();
    if (tid < 256) {
      const int h = tid >> 6, lane = tid & 63;
#pragma unroll
      for (int u = 0; u < 2; ++u) {
        const int d = lane + u * 64;
        const float* vb = kvb + 512 + h * 128 + d;
        float acc = 0.f;
        for (int k = 0; k < 100; ++k) acc += Ps[h][k] * vb[(size_t)(k * 32 + r) * kvstride];
        Bs[h * 128 + d] = acc;             // cav
      }
    }
    __syncthreads();

    // ca proj + residual + LN2
    gemvT<512, 512, 0>(tid, Bs, WcpT, a.ca_proj_b + L * 512, Cs, part);
    {
      const float rv = Cs[tid] + Ts[tid];
      float o;
      BLOCK_LN512(rv, a.ln2_g + L * 512, a.ln2_b + L * 512, o)
      Ts[tid] = o;                         // t2
    }
    __syncthreads();

    // FF
    gemvT<1024, 512, 1>(tid, Ts, W1T, a.ff1_b + L * 1024, F1, part);
    gemvT<512, 1024, 0>(tid, F1, W2T, a.ff2_b + L * 512, Cs, part);
    {
      const float rv = Cs[tid] + Ts[tid];
      float o;
      BLOCK_LN512(rv, a.ln3_g + L * 512, a.ln3_b + L * 512, o)
      Ts[tid] = o;                         // layer output
    }
    __syncthreads();
  }

  // final LN
  {
    const float v = Ts[tid];
    float f;
    BLOCK_LN512(v, a.lnf_g, a.lnf_b, f)
    Ts[tid] = f;
  }
  __syncthreads();

  // fused out1: row r of C(32,2048) = relu(t @ Wo1T + b); 4 outputs/thread
  const float4* wp = (const float4*)a.Wo1T;  // [512][512 quads]
  float ax = 0.f, ay = 0.f, az = 0.f, aw = 0.f;
#pragma unroll 8
  for (int k = 0; k < 512; ++k) {
    const float s = Ts[k];
    const float4 w = wp[(size_t)k * 512 + tid];
    ax += s * w.x; ay += s * w.y; az += s * w.z; aw += s * w.w;
  }
  union { short4v v; bf16 h[4]; } u;
  u.h[0] = __float2bfloat16(fmaxf(ax + a.ob1[4 * tid], 0.f));
  u.h[1] = __float2bfloat16(fmaxf(ay + a.ob1[4 * tid + 1], 0.f));
  u.h[2] = __float2bfloat16(fmaxf(az + a.ob1[4 * tid + 2], 0.f));
  u.h[3] = __float2bfloat16(fmaxf(aw + a.ob1[4 * tid + 3], 0.f));
  *(short4v*)(a.o1b + (size_t)r * 2048 + 4 * tid) = u.v;
  const short4v z = {0, 0, 0, 0};
#pragma unroll
  for (int zr = r + 32; zr < 128; zr += 32)
    *(short4v*)(a.o1b + (size_t)zr * 2048 + 4 * tid) = z;
}

// ---------------------------------------------------------------------------
// out3 split-K reduce (+bias(+guard)+relu) fused with adaptive pool. grid 32.
__global__ __launch_bounds__(256)
void reduce_pool(const float* __restrict__ P, size_t pstride,
                 const float* __restrict__ bias, float* __restrict__ out)
{
  __shared__ float row[NOUT3];
  const int b = blockIdx.x, t = threadIdx.x;
  for (int n = t * 4; n < NOUT3; n += 1024) {
    const size_t o = (size_t)b * NOUT3 + n;
    float4 s = *(const float4*)(P + o);
#pragma unroll
    for (int k = 1; k < 4; ++k) {
      const float4 p = *(const float4*)(P + (size_t)k * pstride + o);
      s.x += p.x; s.y += p.y; s.z += p.z; s.w += p.w;
    }
    row[n]     = fmaxf(s.x + ((n     < FLATIN) ? bias[n]     : 0.f), 0.f);
    row[n + 1] = fmaxf(s.y + ((n + 1 < FLATIN) ? bias[n + 1] : 0.f), 0.f);
    row[n + 2] = fmaxf(s.z + ((n + 2 < FLATIN) ? bias[n + 2] : 0.f), 0.f);
    row[n + 3] = fmaxf(s.w + ((n + 3 < FLATIN) ? bias[n + 3] : 0.f), 0.f);
  }
  __syncthreads();
  for (int i = t; i < 135 * 103; i += 256) {
    const int j = i % 103, r = i / 103;
    const int rs = (r * 143) / 135, re = ((r + 1) * 143 + 134) / 135;
    const int cs = (j * 111) / 103, ce = ((j + 1) * 111 + 102) / 103;
    float s = 0.f;
    for (int rr = rs; rr < re; ++rr)
      for (int cc = cs; cc < ce; ++cc)
        s += row[rr * 111 + cc];
    out[(size_t)b * (135 * 103) + i] = s / (float)((re - rs) * (ce - cs));
  }
}

// ---------------------------------------------------------------------------
extern "C" void kernel_launch(void* const* d_in, const int* in_sizes, int n_in,
                              void* d_out, int out_size, void* d_ws, size_t ws_size,
                              hipStream_t stream)
{
  (void)in_sizes; (void)n_in; (void)out_size; (void)ws_size;

  const float* x          = (const float*)d_in[0];
  const float* fc1_w      = (const float*)d_in[1];
  const float* fc1_b      = (const float*)d_in[2];
  const float* fc2_w      = (const float*)d_in[3];
  const float* fc2_b      = (const float*)d_in[4];
  const float* fc3_w      = (const float*)d_in[5];
  const float* fc3_b      = (const float*)d_in[6];
  const float* out1_w     = (const float*)d_in[7];
  const float* out1_b     = (const float*)d_in[8];
  const float* out2_w     = (const float*)d_in[9];
  const float* out2_b     = (const float*)d_in[10];
  const float* out3_w     = (const float*)d_in[11];
  const float* out3_b     = (const float*)d_in[12];
  const float* enc_qkv_w  = (const float*)d_in[13];
  const float* enc_qkv_b  = (const float*)d_in[14];
  const float* enc_proj_w = (const float*)d_in[15];
  const float* enc_proj_b = (const float*)d_in[16];
  const float* enc_ff1_w  = (const float*)d_in[17];
  const float* enc_ff1_b  = (const float*)d_in[18];
  const float* enc_ff2_w  = (const float*)d_in[19];
  const float* enc_ff2_b  = (const float*)d_in[20];
  const float* enc_ln1_g  = (const float*)d_in[21];
  const float* enc_ln1_b  = (const float*)d_in[22];
  const float* enc_ln2_g  = (const float*)d_in[23];
  const float* enc_ln2_b  = (const float*)d_in[24];
  const float* enc_lnf_g  = (const float*)d_in[25];
  const float* enc_lnf_b  = (const float*)d_in[26];
  const float* dec_sa_qkv_w  = (const float*)d_in[27];
  const float* dec_sa_qkv_b  = (const float*)d_in[28];
  const float* dec_sa_proj_w = (const float*)d_in[29];
  const float* dec_sa_proj_b = (const float*)d_in[30];
  const float* dec_ca_qkv_w  = (const float*)d_in[31];
  const float* dec_ca_qkv_b  = (const float*)d_in[32];
  const float* dec_ca_proj_w = (const float*)d_in[33];
  const float* dec_ca_proj_b = (const float*)d_in[34];
  const float* dec_ff1_w  = (const float*)d_in[35];
  const float* dec_ff1_b  = (const float*)d_in[36];
  const float* dec_ff2_w  = (const float*)d_in[37];
  const float* dec_ff2_b  = (const float*)d_in[38];
  const float* dec_ln1_g  = (const float*)d_in[39];
  const float* dec_ln1_b  = (const float*)d_in[40];
  const float* dec_ln2_g  = (const float*)d_in[41];
  const float* dec_ln2_b  = (const float*)d_in[42];
  const float* dec_ln3_g  = (const float*)d_in[43];
  const float* dec_ln3_b  = (const float*)d_in[44];
  const float* dec_lnf_g  = (const float*)d_in[45];
  const float* dec_lnf_b  = (const float*)d_in[46];

  char* wsp = (char*)d_ws;
  size_t off = 0;
  auto alloc = [&](size_t nbytes) -> char* {
    char* p = wsp + off;
    off += (nbytes + 255) & ~(size_t)255;
    return p;
  };

  bf16* xb     = (bf16*)alloc((size_t)MPAD * KPAD1 * 2);
  bf16* Wb1    = (bf16*)alloc((size_t)4096 * KPAD1 * 2);
  bf16* Wb2    = (bf16*)alloc((size_t)2048 * 4096 * 2);
  bf16* Wb3    = (bf16*)alloc((size_t)512 * 2048 * 2);
  bf16* Wqkvb  = (bf16*)alloc((size_t)2 * 1536 * 512 * 2);
  bf16* Wprojb = (bf16*)alloc((size_t)2 * 512 * 512 * 2);
  bf16* Wff1b  = (bf16*)alloc((size_t)2 * 1024 * 512 * 2);
  bf16* Wff2b  = (bf16*)alloc((size_t)2 * 512 * 1024 * 2);
  bf16* Wkv2b  = (bf16*)alloc((size_t)2048 * 512 * 2);
  int*   nz      = (int*)alloc(ROWS * 4);
  int*   padmask = (int*)alloc(ROWS * 4);
  int*   idx     = (int*)alloc(MPAD * 4);
  int*   pos     = (int*)alloc(ROWS * 4);
  int*   cnt     = (int*)alloc(256);
  float* kvbias  = (float*)alloc(2048 * 4);
  bf16* h1c = (bf16*)alloc((size_t)MPAD * 4096 * 2);
  bf16* h2c = (bf16*)alloc((size_t)MPAD * 2048 * 2);
  float* hf  = (float*)alloc((size_t)ROWS * 512 * 4);
  bf16* hb = (bf16*)alloc((size_t)ROWS * 512 * 2);
  float* qkvbuf = (float*)alloc((size_t)ROWS * 1536 * 4);
  bf16* attnb = (bf16*)alloc((size_t)ROWS * 512 * 2);
  float* pjf  = (float*)alloc((size_t)ROWS * 512 * 4);
  bf16* f1b = (bf16*)alloc((size_t)ROWS * 1024 * 2);
  float* f2f  = (float*)alloc((size_t)ROWS * 512 * 4);
  bf16* memb = (bf16*)alloc((size_t)ROWS * 512 * 2);
  float* kv01 = (float*)alloc((size_t)ROWS * 2048 * 4);
  float* WvT[2]  = { (float*)alloc(512 * 512 * 4), (float*)alloc(512 * 512 * 4) };
  float* WpT[2]  = { (float*)alloc(512 * 512 * 4), (float*)alloc(512 * 512 * 4) };
  float* WqT[2]  = { (float*)alloc(512 * 512 * 4), (float*)alloc(512 * 512 * 4) };
  float* WcpT[2] = { (float*)alloc(512 * 512 * 4), (float*)alloc(512 * 512 * 4) };
  float* W1T[2]  = { (float*)alloc(512 * 1024 * 4), (float*)alloc(512 * 1024 * 4) };
  float* W2T[2]  = { (float*)alloc(1024 * 512 * 4), (float*)alloc(1024 * 512 * 4) };
  float* Wo1T    = (float*)alloc((size_t)512 * 2048 * 4);
  float* fcP  = (float*)alloc((size_t)4 * MPAD * 4096 * 4);   // 218 MB
  float* encP = (float*)alloc((size_t)2 * ROWS * 1536 * 4);   // aliases

  float* outP = fcP;                                           // <=33 MB
  bf16* o1b  = (bf16*)((char*)encP + ((size_t)20 << 20));
  bf16* o2b  = (bf16*)((char*)encP + ((size_t)22 << 20));

  const size_t psF1 = (size_t)MPAD * 4096;
  const size_t psF2 = (size_t)MPAD * 2048;
  const size_t psF3 = (size_t)MPAD * 512;

  // ---- phase 0: merged prep (conv_x | cvt | fc1 cvt | transpose), compact --
  {
    PrepArgs pa;
    pa.x = x; pa.xb = xb; pa.nz = nz; pa.nConv = ROWS + 1;
    const float* srcs[8] = { enc_qkv_w, enc_proj_w, enc_ff1_w, enc_ff2_w,
                             dec_ca_qkv_w + (size_t)512 * 512,
                             dec_ca_qkv_w + (size_t)(1536 + 512) * 512,
                             fc2_w, fc3_w };
    bf16* dsts[8] = { Wqkvb, Wprojb, Wff1b, Wff2b,
                      Wkv2b, Wkv2b + (size_t)1024 * 512, Wb2, Wb3 };
    const int counts[8] = { 2*1536*512, 2*512*512, 2*1024*512, 2*512*1024,
                            1024*512, 1024*512, 2048*4096, 512*2048 };
    int c = 0;
    for (int i = 0; i < 8; ++i) { pa.cv.src[i] = srcs[i]; pa.cv.dst[i] = dsts[i];
                                  pa.cv.cum[i] = c; c += counts[i] >> 11; }
    pa.nCvt = c;
    pa.fc1w = fc1_w; pa.wb1 = Wb1; pa.nFc1 = 4096;
    const float* tsr[13];
    float* tds[13];
    int R[13], C[13];
    int n = 0;
    for (int L = 0; L < 2; ++L) {
      tsr[n] = dec_sa_qkv_w + (size_t)L * 1536 * 512 + (size_t)1024 * 512;
      tds[n] = WvT[L]; R[n] = 512; C[n] = 512; ++n;
      tsr[n] = dec_sa_proj_w + (size_t)L * 512 * 512;
      tds[n] = WpT[L]; R[n] = 512; C[n] = 512; ++n;
      tsr[n] = dec_ca_qkv_w + (size_t)L * 1536 * 512;
      tds[n] = WqT[L]; R[n] = 512; C[n] = 512; ++n;
      tsr[n] = dec_ca_proj_w + (size_t)L * 512 * 512;
      tds[n] = WcpT[L]; R[n] = 512; C[n] = 512; ++n;
      tsr[n] = dec_ff1_w + (size_t)L * 1024 * 512;
      tds[n] = W1T[L]; R[n] = 1024; C[n] = 512; ++n;
      tsr[n] = dec_ff2_w + (size_t)L * 512 * 1024;
      tds[n] = W2T[L]; R[n] = 512; C[n] = 1024; ++n;
    }
    tsr[n] = out1_w; tds[n] = Wo1T; R[n] = 2048; C[n] = 512; ++n;
    int tc = 0;
    for (int i = 0; i < 13; ++i) {
      pa.tr.src[i] = tsr[i]; pa.tr.dst[i] = tds[i];
      pa.tr.R[i] = R[i]; pa.tr.C[i] = C[i];
      pa.tr.cum[i] = tc; tc += (R[i] >> 6) * (C[i] >> 6);
    }
    prep_kernel<<<pa.nConv + pa.nCvt + pa.nFc1 + tc, 256, 0, stream>>>(pa);
  }
  compact_kernel<<<1, 256, 0, stream>>>(nz, idx, pos, cnt, padmask,
                                        dec_ca_qkv_b, kvbias);

  // ---- phase 1: input MLP (split-K) ----
  gemm_bf16<1><<<26 * 32 * 2, 256, 0, stream>>>(xb, Wb1, idx, cnt, fcP,
      KPAD1, 4096, 26, 2, psF1);
  reduce_kernel<1, 0, 1><<<dim3(4, MPAD), 256, 0, stream>>>(fcP, psF1, 2,
      fc1_b, nullptr, h1c, 4096, cnt);
  gemm_bf16<0><<<26 * 16 * 4, 256, 0, stream>>>(h1c, Wb2, nullptr, cnt, fcP,
      4096, 2048, 26, 4, psF2);
  reduce_kernel<1, 0, 1><<<dim3(2, MPAD), 256, 0, stream>>>(fcP, psF2, 4,
      fc2_b, nullptr, h2c, 2048, cnt);
  gemm_bf16<0><<<26 * 4 * 4, 256, 0, stream>>>(h2c, Wb3, nullptr, cnt, fcP,
      2048, 512, 26, 4, psF3);
  scatter_pe_reduce<<<ROWS, 256, 0, stream>>>(fcP, psF3, 4, pos, fc3_b, hf, hb);

  // ---- phase 2: encoder ----
  for (int L = 0; L < 2; ++L) {
    gemm_direct<0, 1, 0><<<25 * 12, 256, 0, stream>>>(hb, Wqkvb + (size_t)L * 1536 * 512,
        enc_qkv_b + L * 1536, qkvbuf, nullptr, 512, 1536, 25);
    enc_attn_kernel<<<dim3(128, 25), 256, 0, stream>>>(qkvbuf, padmask, attnb);
    gemm_direct<0, 1, 0><<<25 * 4, 256, 0, stream>>>(attnb, Wprojb + (size_t)L * 512 * 512,
        enc_proj_b + L * 512, pjf, nullptr, 512, 512, 25);
    ln_kernel<<<ROWS, 256, 0, stream>>>(hf, pjf, enc_ln1_g + L * 512, enc_ln1_b + L * 512,
        nullptr, nullptr, 0, hf, hb);
    gemm_direct<1, 0, 1><<<25 * 8, 256, 0, stream>>>(hb, Wff1b + (size_t)L * 1024 * 512,
        enc_ff1_b + L * 1024, nullptr, f1b, 512, 1024, 25);
    gemm_direct<0, 1, 0><<<25 * 4, 256, 0, stream>>>(f1b, Wff2b + (size_t)L * 512 * 1024,
        enc_ff2_b + L * 512, f2f, nullptr, 1024, 512, 25);
    if (L == 0) {
      ln_kernel<<<ROWS, 256, 0, stream>>>(hf, f2f, enc_ln2_g, enc_ln2_b,
          nullptr, nullptr, 0, hf, hb);
    } else {
      ln_kernel<<<ROWS, 256, 0, stream>>>(hf, f2f, enc_ln2_g + 512, enc_ln2_b + 512,
          enc_lnf_g, enc_lnf_b, 1, nullptr, memb);
    }
  }

  // ---- decoder KV (both layers, one GEMM) ----
  gemm_direct<0, 1, 0><<<25 * 16, 256, 0, stream>>>(memb, Wkv2b, kvbias,
      kv01, nullptr, 512, 2048, 25);

  // ---- phase 3: fused decoder (both layers + final LN + out1) ----
  {
    DecArgs da;
    da.kv01 = kv01;
    da.WvT0 = WvT[0];  da.WvT1 = WvT[1];
    da.WpT0 = WpT[0];  da.WpT1 = WpT[1];
    da.WqT0 = WqT[0];  da.WqT1 = WqT[1];
    da.WcpT0 = WcpT[0]; da.WcpT1 = WcpT[1];
    da.W1T0 = W1T[0];  da.W1T1 = W1T[1];
    da.W2T0 = W2T[0];  da.W2T1 = W2T[1];
    da.sa_qkv_b = dec_sa_qkv_b; da.sa_proj_b = dec_sa_proj_b;
    da.ca_qkv_b = dec_ca_qkv_b; da.ca_proj_b = dec_ca_proj_b;
    da.ff1_b = dec_ff1_b; da.ff2_b = dec_ff2_b;
    da.ln1_g = dec_ln1_g; da.ln1_b = dec_ln1_b;
    da.ln2_g = dec_ln2_g; da.ln2_b = dec_ln2_b;
    da.ln3_g = dec_ln3_g; da.ln3_b = dec_ln3_b;
    da.lnf_g = dec_lnf_g; da.lnf_b = dec_lnf_b;
    da.Wo1T = Wo1T; da.ob1 = out1_b;
    da.o1b = o1b;
    dec2_layer<<<32, 512, 0, stream>>>(da);
  }

  // ---- phase 4: output MLP (fp32-weight GEMMs, conversion fused) ----
  gemm_w32<<<32 * 4, 256, 0, stream>>>(o1b, out2_w, outP,
      2048, 4096, 4, (size_t)128 * 4096, 4096);
  reduce_kernel<1, 0, 1><<<dim3(4, 128), 256, 0, stream>>>(outP, (size_t)128 * 4096, 4,
      out2_b, nullptr, o2b, 4096, nullptr);
  gemm_w32<<<125 * 4, 256, 0, stream>>>(o2b, out3_w, outP,
      4096, NOUT3, 4, (size_t)128 * NOUT3, FLATIN);
  reduce_pool<<<32, 256, 0, stream>>>(outP, (size_t)128 * NOUT3, out3_b, (float*)d_out);
}

// Round 17
// 1300.953 us; speedup vs baseline: 1.1868x; 1.1868x over previous
//
#include <hip/hip_runtime.h>
#include <hip/hip_bf16.h>

// ---------------------------------------------------------------------------
#define SEQ   100
#define BATCH 32
#define FLATIN 15873
#define KPAD1  16384
#define ROWS   3200
#define MPAD   3328
#define NOUT3  16000

typedef __attribute__((ext_vector_type(8))) short short8;
typedef __attribute__((ext_vector_type(4))) short short4v;
typedef __attribute__((ext_vector_type(4))) float f32x4;
typedef __hip_bfloat16 bf16;

__device__ __forceinline__ void gload_lds16(const void* g, void* l) {
  __builtin_amdgcn_global_load_lds((const __attribute__((address_space(1))) void*)g,
                                   (__attribute__((address_space(3))) void*)l, 16, 0, 0);
}

// bijective XCD chunk swizzle (m204)
__device__ __forceinline__ int xcd_swizzle(int id, int nwg) {
  const int q = nwg >> 3, r = nwg & 7;
  const int x = id & 7, p = id >> 3;
  return (x < r ? x * (q + 1) : r * (q + 1) + (x - r) * q) + p;
}

// ---------------------------------------------------------------------------
// Shared GEMM body: stage 128x64 A/B tiles (both-sides chunk swizzle), MFMA.
#define GEMM_BODY(KBEG, KEND)                                                   \
  const int tid  = threadIdx.x;                                                 \
  const int lane = tid & 63;                                                    \
  const int wid  = tid >> 6;                                                    \
  const int wr = (wid >> 1) << 6;                                               \
  const int wc = (wid & 1) << 6;                                                \
  f32x4 acc[4][4];                                                              \
  _Pragma("unroll") for (int i = 0; i < 4; ++i)                                 \
  _Pragma("unroll") for (int j = 0; j < 4; ++j)                                 \
      acc[i][j] = (f32x4){0.f, 0.f, 0.f, 0.f};                                  \
  const int srow = (wid << 3) + (lane >> 3);                                    \
  const int scs  = lane & 7;                                                    \
  const int gcol = ((scs ^ (srow & 7)) << 3);                                   \
  const bf16* arow[4];                                                          \
  const bf16* brow[4];                                                          \
  _Pragma("unroll") for (int j = 0; j < 4; ++j) {                               \
    const int row = (j << 5) + srow;                                            \
    const int gr = GATHER ? idx[m0 + row] : (m0 + row);                         \
    arow[j] = A + (size_t)gr * K + gcol;                                        \
    brow[j] = W + (size_t)(n0 + row) * K + gcol;                                \
  }                                                                             \
  for (int k0 = (KBEG); k0 < (KEND); k0 += 64) {                                \
    __syncthreads();                                                            \
    _Pragma("unroll") for (int j = 0; j < 4; ++j) {                             \
      short* la = As + (((j << 2) + wid) << 9);                                 \
      short* lb = Bs + (((j << 2) + wid) << 9);                                 \
      gload_lds16(arow[j] + k0, la);                                            \
      gload_lds16(brow[j] + k0, lb);                                            \
    }                                                                           \
    __syncthreads();                                                            \
    _Pragma("unroll") for (int kk = 0; kk < 2; ++kk) {                          \
      short8 af[4], bfv[4];                                                     \
      _Pragma("unroll") for (int i = 0; i < 4; ++i) {                           \
        const int mr = wr + (i << 4) + (lane & 15);                             \
        const int cg = (kk << 2) + (lane >> 4);                                 \
        af[i]  = *(const short8*)(As + mr * 64 + ((cg ^ (mr & 7)) << 3));       \
        const int nr = wc + (i << 4) + (lane & 15);                             \
        bfv[i] = *(const short8*)(Bs + nr * 64 + ((cg ^ (nr & 7)) << 3));       \
      }                                                                         \
      _Pragma("unroll") for (int i = 0; i < 4; ++i)                             \
      _Pragma("unroll") for (int j = 0; j < 4; ++j)                             \
          acc[i][j] = __builtin_amdgcn_mfma_f32_16x16x32_bf16(af[i], bfv[j],    \
                                                              acc[i][j], 0,0,0);\
    }                                                                           \
  }

// Split-K partial-output GEMM. mt-minor linearization.
template<int GATHER>
__global__ __launch_bounds__(256)
void gemm_bf16(const bf16* __restrict__ A, const bf16* __restrict__ W,
               const int* __restrict__ idx, const int* __restrict__ cnt,
               float* __restrict__ P,
               int K, int ldc, int mtiles, int ksl, size_t pstride)
{
  __shared__ __align__(16) short lds[16384];
  short* As = lds;
  short* Bs = lds + 8192;
  const int wg = xcd_swizzle(blockIdx.x, gridDim.x);
  const int mt = wg % mtiles;
  const int g  = wg / mtiles;
  const int nt = g / ksl;
  const int ks = g % ksl;
  const int m0 = mt << 7;
  const int n0 = nt << 7;
  if (cnt && m0 >= cnt[0]) return;
  const int Klen = K / ksl;
  const int kbeg = ks * Klen;

  GEMM_BODY(kbeg, kbeg + Klen)

  float* Pout = P + (size_t)ks * pstride;
  const int fr = lane & 15, fq = lane >> 4;
#pragma unroll
  for (int j = 0; j < 4; ++j) {
    const int n = n0 + wc + (j << 4) + fr;
#pragma unroll
    for (int i = 0; i < 4; ++i)
#pragma unroll
      for (int r = 0; r < 4; ++r) {
        const int m = m0 + wr + (i << 4) + (fq << 2) + r;
        Pout[(size_t)m * ldc + n] = acc[i][j][r];
      }
  }
}

// Direct GEMM with fused bias/relu epilogue
template<int RELU, int OF32, int OB16>
__global__ __launch_bounds__(256)
void gemm_direct(const bf16* __restrict__ A, const bf16* __restrict__ W,
                 const float* __restrict__ bias, float* __restrict__ Cf,
                 bf16* __restrict__ Cb, int K, int ldc, int mtiles)
{
  __shared__ __align__(16) short lds[16384];
  short* As = lds;
  short* Bs = lds + 8192;
  const int GATHER = 0;
  const int* idx = nullptr;
  const int wg = xcd_swizzle(blockIdx.x, gridDim.x);
  const int m0 = (wg % mtiles) << 7;
  const int n0 = (wg / mtiles) << 7;

  GEMM_BODY(0, K)

  const int fr = lane & 15, fq = lane >> 4;
#pragma unroll
  for (int j = 0; j < 4; ++j) {
    const int n = n0 + wc + (j << 4) + fr;
    const float bb = bias[n];
#pragma unroll
    for (int i = 0; i < 4; ++i)
#pragma unroll
      for (int r = 0; r < 4; ++r) {
        const int m = m0 + wr + (i << 4) + (fq << 2) + r;
        float v = acc[i][j][r] + bb;
        if (RELU) v = fmaxf(v, 0.f);
        if (OF32) Cf[(size_t)m * ldc + n] = v;
        if (OB16) Cb[(size_t)m * ldc + n] = __float2bfloat16(v);
      }
  }
}

// ---------------------------------------------------------------------------
// Split-K GEMM with fp32 B-side (conversion fused into staging; rule #21:
// inverse-swizzled write + swizzled read). B rows clamped to wrows-1.
__global__ __launch_bounds__(256)
void gemm_w32(const bf16* __restrict__ A, const float* __restrict__ W32,
              float* __restrict__ P, int K, int ldc, int ksl, size_t pstride,
              int wrows)
{
  __shared__ __align__(16) short lds[16384];
  short* As = lds;
  short* Bs = lds + 8192;
  const int wg = xcd_swizzle(blockIdx.x, gridDim.x);
  const int nt = wg / ksl;
  const int ks = wg % ksl;
  const int m0 = 0;
  const int n0 = nt << 7;
  const int Klen = K / ksl;
  const int kbeg = ks * Klen;
  const int kend = kbeg + Klen;

  const int tid  = threadIdx.x;
  const int lane = tid & 63;
  const int wid  = tid >> 6;
  const int wr = (wid >> 1) << 6;
  const int wc = (wid & 1) << 6;

  f32x4 acc[4][4];
#pragma unroll
  for (int i = 0; i < 4; ++i)
#pragma unroll
    for (int j = 0; j < 4; ++j) acc[i][j] = (f32x4){0.f, 0.f, 0.f, 0.f};

  const int srow = (wid << 3) + (lane >> 3);
  const int scs  = lane & 7;
  const int gcol = ((scs ^ (srow & 7)) << 3);

  const bf16* arow[4];
#pragma unroll
  for (int j = 0; j < 4; ++j)
    arow[j] = A + (size_t)(m0 + (j << 5) + srow) * K + gcol;

  const float* wsrc[4];
  int bslot[4];
#pragma unroll
  for (int i = 0; i < 4; ++i) {
    const int q = (i << 8) + tid;
    const int row = q >> 3, c = q & 7;
    const int wrow = min(n0 + row, wrows - 1);
    wsrc[i] = W32 + (size_t)wrow * K + (c << 3);
    bslot[i] = row * 64 + ((c ^ (row & 7)) << 3);
  }

  for (int k0 = kbeg; k0 < kend; k0 += 64) {
    __syncthreads();
#pragma unroll
    for (int j = 0; j < 4; ++j)
      gload_lds16(arow[j] + k0, As + (((j << 2) + wid) << 9));
#pragma unroll
    for (int i = 0; i < 4; ++i) {
      const float4 w0 = *(const float4*)(wsrc[i] + k0);
      const float4 w1 = *(const float4*)(wsrc[i] + k0 + 4);
      union { short8 v; bf16 h[8]; } pk;
      pk.h[0] = __float2bfloat16(w0.x); pk.h[1] = __float2bfloat16(w0.y);
      pk.h[2] = __float2bfloat16(w0.z); pk.h[3] = __float2bfloat16(w0.w);
      pk.h[4] = __float2bfloat16(w1.x); pk.h[5] = __float2bfloat16(w1.y);
      pk.h[6] = __float2bfloat16(w1.z); pk.h[7] = __float2bfloat16(w1.w);
      *(short8*)(Bs + bslot[i]) = pk.v;
    }
    __syncthreads();
#pragma unroll
    for (int kk = 0; kk < 2; ++kk) {
      short8 af[4], bfv[4];
#pragma unroll
      for (int i = 0; i < 4; ++i) {
        const int mr = wr + (i << 4) + (lane & 15);
        const int cg = (kk << 2) + (lane >> 4);
        af[i]  = *(const short8*)(As + mr * 64 + ((cg ^ (mr & 7)) << 3));
        const int nr = wc + (i << 4) + (lane & 15);
        bfv[i] = *(const short8*)(Bs + nr * 64 + ((cg ^ (nr & 7)) << 3));
      }
#pragma unroll
      for (int i = 0; i < 4; ++i)
#pragma unroll
        for (int j = 0; j < 4; ++j)
          acc[i][j] = __builtin_amdgcn_mfma_f32_16x16x32_bf16(af[i], bfv[j], acc[i][j], 0, 0, 0);
    }
  }

  float* Pout = P + (size_t)ks * pstride;
  const int fr = lane & 15, fq = lane >> 4;
#pragma unroll
  for (int j = 0; j < 4; ++j) {
    const int n = n0 + wc + (j << 4) + fr;
#pragma unroll
    for (int i = 0; i < 4; ++i)
#pragma unroll
      for (int r = 0; r < 4; ++r) {
        const int m = m0 + wr + (i << 4) + (fq << 2) + r;
        Pout[(size_t)m * ldc + n] = acc[i][j][r];
      }
  }
}

// ---------------------------------------------------------------------------
// Split-K reduce: C = sum_ks P[ks] + bias [, relu]
template<int RELU, int OF32, int OB16>
__global__ __launch_bounds__(256)
void reduce_kernel(const float* __restrict__ P, size_t pstride, int ksl,
                   const float* __restrict__ bias, float* __restrict__ Cf,
                   bf16* __restrict__ Cb, int N, const int* __restrict__ cnt)
{
  const int row = blockIdx.y;
  if (cnt) { const int cp = (cnt[0] + 127) & ~127; if (row >= cp) return; }
  const int n = (blockIdx.x * 256 + threadIdx.x) * 4;
  if (n >= N) return;
  const size_t o = (size_t)row * N + n;
  const float4 b4 = *(const float4*)(bias + n);
  float4 s = *(const float4*)(P + o);
  for (int k = 1; k < ksl; ++k) {
    const float4 p = *(const float4*)(P + (size_t)k * pstride + o);
    s.x += p.x; s.y += p.y; s.z += p.z; s.w += p.w;
  }
  s.x += b4.x; s.y += b4.y; s.z += b4.z; s.w += b4.w;
  if (RELU) {
    s.x = fmaxf(s.x, 0.f); s.y = fmaxf(s.y, 0.f);
    s.z = fmaxf(s.z, 0.f); s.w = fmaxf(s.w, 0.f);
  }
  if (OF32) *(float4*)(Cf + o) = s;
  if (OB16) {
    union { short4v v; bf16 h[4]; } u;
    u.h[0] = __float2bfloat16(s.x);
    u.h[1] = __float2bfloat16(s.y);
    u.h[2] = __float2bfloat16(s.z);
    u.h[3] = __float2bfloat16(s.w);
    *(short4v*)(Cb + o) = u.v;
  }
}

// Compaction + padding mask + decoder-KV bias concat (single block)
__global__ __launch_bounds__(256)
void compact_kernel(const int* __restrict__ nz, int* __restrict__ idx,
                    int* __restrict__ pos, int* __restrict__ cnt,
                    int* __restrict__ pad,
                    const float* __restrict__ dkvb, float* __restrict__ kvbias)
{
  __shared__ int wsum[4];
  __shared__ int total;
  const int t = threadIdx.x;
  int loc[13];
  int c = 0;
#pragma unroll
  for (int i = 0; i < 13; ++i) {
    const int m = t * 13 + i;
    loc[i] = (m < ROWS) ? nz[m] : 0;
    c += loc[i];
  }
  int v = c;
#pragma unroll
  for (int o = 1; o < 64; o <<= 1) {
    const int u = __shfl_up(v, o);
    if ((t & 63) >= o) v += u;
  }
  if ((t & 63) == 63) wsum[t >> 6] = v;
  __syncthreads();
  int wbase = 0;
  for (int w = 0; w < (t >> 6); ++w) wbase += wsum[w];
  int p = wbase + v - c;
#pragma unroll
  for (int i = 0; i < 13; ++i) {
    const int m = t * 13 + i;
    if (m < ROWS) {
      if (loc[i]) { idx[p] = m; pos[m] = p; ++p; }
      else pos[m] = -1;
    }
  }
  if (t == 255) total = p;
  __syncthreads();
  const int count = total;
  if (t == 0) cnt[0] = count + 1;
  for (int i = count + t; i < MPAD; i += 256) idx[i] = ROWS;
  for (int m = t; m < ROWS; m += 256) if (pos[m] < 0) pos[m] = count;
  if (t < 32) {
    int any = 0;
    for (int s = 99; s >= 0; --s) {
      any |= nz[t * 100 + s];
      pad[t * 100 + s] = (s > 0 && !any) ? 1 : 0;
    }
  }
#pragma unroll
  for (int i = t; i < 2048; i += 256) {
    const int L = i >> 10, j = i & 1023;
    kvbias[i] = dkvb[L * 1536 + 512 + j];
  }
}

// ---------------------------------------------------------------------------
// Merged prep kernel: conv_x | multi-cvt | fc1 padded cvt | multi transpose
// (transpose now emits bf16 decoder/out1 weights).
struct CvtArgs {
  const float* src[8];
  bf16* dst[8];
  int cum[8];
};
struct TrArgs {
  const float* src[13];
  bf16* dst[13];
  int R[13], C[13], cum[13];
};
struct PrepArgs {
  CvtArgs cv;
  TrArgs tr;
  const float* x;
  bf16* xb;
  int* nz;
  const float* fc1w;
  bf16* wb1;
  int nConv, nCvt, nFc1;   // block counts of first three partitions
};
__global__ __launch_bounds__(256)
void prep_kernel(PrepArgs a)
{
  __shared__ float tbuf[64][65];
  __shared__ int sred[4];
  const int bid0 = blockIdx.x;
  if (bid0 < a.nConv) {
    const int m = bid0;                    // 0..ROWS
    const int t = threadIdx.x;
    bf16* dst = a.xb + (size_t)m * KPAD1;
    if (m == ROWS) {
      const __hip_bfloat162 z2 = {__float2bfloat16(0.f), __float2bfloat16(0.f)};
      for (int c = t; c < (KPAD1 >> 1); c += 256) *(__hip_bfloat162*)(dst + 2 * c) = z2;
      return;
    }
    const float* src = a.x + (size_t)m * FLATIN;
    int any = 0;
    for (int c = t; c < (KPAD1 >> 1); c += 256) {
      const int c0 = 2 * c;
      const float v0 = (c0 < FLATIN) ? src[c0] : 0.f;
      const float v1 = (c0 + 1 < FLATIN) ? src[c0 + 1] : 0.f;
      any |= (v0 != 0.f) | (v1 != 0.f);
      __hip_bfloat162 pr;
      pr.x = __float2bfloat16(v0);
      pr.y = __float2bfloat16(v1);
      *(__hip_bfloat162*)(dst + c0) = pr;
    }
    any = __any(any) ? 1 : 0;
    if ((t & 63) == 0) sred[t >> 6] = any;
    __syncthreads();
    if (t == 0) a.nz[m] = sred[0] | sred[1] | sred[2] | sred[3];
  } else if (bid0 < a.nConv + a.nCvt) {
    const int bid = bid0 - a.nConv;
    int seg = 0;
#pragma unroll
    for (int i = 1; i < 8; ++i) if (bid >= a.cv.cum[i]) seg = i;
    const size_t e0 = ((size_t)(bid - a.cv.cum[seg]) << 11) + (threadIdx.x << 3);
    const float4 v0 = *(const float4*)(a.cv.src[seg] + e0);
    const float4 v1 = *(const float4*)(a.cv.src[seg] + e0 + 4);
    union { short8 v; bf16 h[8]; } pk;
    pk.h[0] = __float2bfloat16(v0.x); pk.h[1] = __float2bfloat16(v0.y);
    pk.h[2] = __float2bfloat16(v0.z); pk.h[3] = __float2bfloat16(v0.w);
    pk.h[4] = __float2bfloat16(v1.x); pk.h[5] = __float2bfloat16(v1.y);
    pk.h[6] = __float2bfloat16(v1.z); pk.h[7] = __float2bfloat16(v1.w);
    *(short8*)(a.cv.dst[seg] + e0) = pk.v;
  } else if (bid0 < a.nConv + a.nCvt + a.nFc1) {
    const int r = bid0 - a.nConv - a.nCvt;  // 0..4095
    const float* src = a.fc1w + (size_t)r * FLATIN;
    bf16* dst = a.wb1 + (size_t)r * KPAD1;
#pragma unroll
    for (int u = 0; u < KPAD1 / 2048; ++u) {
      const int c0 = u * 2048 + threadIdx.x * 8;
      union { short8 v; bf16 h[8]; } pk;
      if (c0 + 8 <= FLATIN) {
        const float4 p = *(const float4*)(src + c0);
        const float4 q = *(const float4*)(src + c0 + 4);
        pk.h[0] = __float2bfloat16(p.x); pk.h[1] = __float2bfloat16(p.y);
        pk.h[2] = __float2bfloat16(p.z); pk.h[3] = __float2bfloat16(p.w);
        pk.h[4] = __float2bfloat16(q.x); pk.h[5] = __float2bfloat16(q.y);
        pk.h[6] = __float2bfloat16(q.z); pk.h[7] = __float2bfloat16(q.w);
      } else {
#pragma unroll
        for (int i = 0; i < 8; ++i)
          pk.h[i] = __float2bfloat16((c0 + i < FLATIN) ? src[c0 + i] : 0.f);
      }
      *(short8*)(dst + c0) = pk.v;
    }
  } else {
    const int bid = bid0 - a.nConv - a.nCvt - a.nFc1;
    int seg = 0;
#pragma unroll
    for (int i = 1; i < 13; ++i) if (bid >= a.tr.cum[i]) seg = i;
    const int local = bid - a.tr.cum[seg];
    const int R = a.tr.R[seg], C = a.tr.C[seg];
    const int tilesC = C >> 6;
    const int r0 = (local / tilesC) << 6;
    const int c0 = (local % tilesC) << 6;
    const int tx = threadIdx.x & 63, ty = threadIdx.x >> 6;
    const float* s = a.tr.src[seg];
    bf16* d = a.tr.dst[seg];
#pragma unroll
    for (int i = 0; i < 16; ++i) {
      const int rr = (ty << 4) + i;
      tbuf[rr][tx] = s[(size_t)(r0 + rr) * C + c0 + tx];
    }
    __syncthreads();
#pragma unroll
    for (int i = 0; i < 16; ++i) {
      const int cc = (ty << 4) + i;
      d[(size_t)(c0 + cc) * R + r0 + tx] = __float2bfloat16(tbuf[tx][cc]);
    }
  }
}

// fc3 reduce + bias + relu + scatter + inline PE
__global__ __launch_bounds__(256)
void scatter_pe_reduce(const float* __restrict__ P, size_t pstride, int ksl,
                       const int* __restrict__ pos, const float* __restrict__ bias,
                       float* __restrict__ hf, bf16* __restrict__ hb)
{
  const int m = blockIdx.x;
  const int s = m % 100, b = m / 100;
  const int src = pos[m];
  const int t = threadIdx.x;
  const size_t sb = (size_t)src * 512;
  const size_t db = (size_t)(s * 32 + b) * 512;
#pragma unroll
  for (int u = 0; u < 2; ++u) {
    const int d = t + u * 256;
    float v = bias[d];
    for (int k = 0; k < ksl; ++k) v += P[(size_t)k * pstride + sb + d];
    const float div = expf((float)(2 * (d >> 1)) * (-9.210340371976184f / 512.f));
    const float arg = (float)s * div;
    const float pe = (d & 1) ? cosf(arg) : sinf(arg);
    v = fmaxf(v, 0.f) + pe;
    hf[db + d] = v;
    hb[db + d] = __float2bfloat16(v);
  }
}

// ---------------------------------------------------------------------------
// LayerNorm over D=512 (+ optional second, final LN fused)
__global__ __launch_bounds__(256)
void ln_kernel(const float* __restrict__ x, const float* __restrict__ res,
               const float* __restrict__ g, const float* __restrict__ bta,
               const float* __restrict__ gf, const float* __restrict__ bf_,
               int dofinal, float* __restrict__ y, bf16* __restrict__ yb)
{
  __shared__ float rs[4], rss[4];
  const int row = blockIdx.x;
  const int t = threadIdx.x;
  const size_t base = (size_t)row * 512;
  float v0 = x[base + t];
  float v1 = x[base + t + 256];
  if (res) { v0 += res[base + t]; v1 += res[base + t + 256]; }
  float o0, o1;
#pragma unroll
  for (int pass = 0; pass < 2; ++pass) {
    float s = v0 + v1, ss = v0 * v0 + v1 * v1;
#pragma unroll
    for (int o = 32; o > 0; o >>= 1) { s += __shfl_xor(s, o); ss += __shfl_xor(ss, o); }
    if ((t & 63) == 0) { rs[t >> 6] = s; rss[t >> 6] = ss; }
    __syncthreads();
    s = rs[0] + rs[1] + rs[2] + rs[3];
    ss = rss[0] + rss[1] + rss[2] + rss[3];
    __syncthreads();
    const float mean = s * (1.f / 512.f);
    const float var = ss * (1.f / 512.f) - mean * mean;
    const float inv = rsqrtf(var + 1e-5f);
    const float* gg = (pass == 0) ? g : gf;
    const float* bb = (pass == 0) ? bta : bf_;
    o0 = (v0 - mean) * inv * gg[t] + bb[t];
    o1 = (v1 - mean) * inv * gg[t + 256] + bb[t + 256];
    if (pass == 1 || !dofinal) break;
    v0 = o0; v1 = o1;
  }
  if (y) {
    y[base + t] = o0;
    y[base + t + 256] = o1;
  }
  if (yb) {
    yb[base + t] = __float2bfloat16(o0);
    yb[base + t + 256] = __float2bfloat16(o1);
  }
}

// ---------------------------------------------------------------------------
// Encoder self-attention. grid (128 bh, 25 qg): 4 q's per block.
__global__ __launch_bounds__(256)
void enc_attn_kernel(const float* __restrict__ qkv, const int* __restrict__ pad,
                     bf16* __restrict__ ob)
{
  __shared__ float Ks[100][129];
  __shared__ float Qs[128];
  __shared__ float Ps[100];
  __shared__ float red[4];
  const int bh = blockIdx.x;
  const int b = bh >> 2, h = bh & 3;
  const int q0 = blockIdx.y * 4;
  const int t = threadIdx.x;
  for (int i = t; i < 12800; i += 256) {
    const int s = i >> 7, d = i & 127;
    Ks[s][d] = qkv[(size_t)(s * 32 + b) * 1536 + 512 + h * 128 + d];
  }
  const int masked = (t < 100) ? pad[b * 100 + t] : 0;
  const float scale = 0.08838834764831845f;
  for (int qi = 0; qi < 4; ++qi) {
    const int q = q0 + qi;
    __syncthreads();
    if (t < 128) Qs[t] = qkv[(size_t)(q * 32 + b) * 1536 + h * 128 + t];
    __syncthreads();
    float sc = -3e38f;
    if (t < 100) {
      const float* kr = &Ks[t][0];
      float a = 0.f;
#pragma unroll 16
      for (int d = 0; d < 128; ++d) a += Qs[d] * kr[d];
      sc = masked ? -1e9f : (a * scale);
    }
    float mx = sc;
#pragma unroll
    for (int o = 32; o > 0; o >>= 1) mx = fmaxf(mx, __shfl_xor(mx, o));
    if ((t & 63) == 0) red[t >> 6] = mx;
    __syncthreads();
    mx = fmaxf(fmaxf(red[0], red[1]), fmaxf(red[2], red[3]));
    const float e = (t < 100) ? expf(sc - mx) : 0.f;
    float sm = e;
#pragma unroll
    for (int o = 32; o > 0; o >>= 1) sm += __shfl_xor(sm, o);
    __syncthreads();
    if ((t & 63) == 0) red[t >> 6] = sm;
    __syncthreads();
    sm = red[0] + red[1] + red[2] + red[3];
    if (t < 100) Ps[t] = e;
    __syncthreads();
    if (t < 128) {
      float a = 0.f;
      const float* vb = qkv + 1024 + h * 128 + t;
      for (int k = 0; k < 100; ++k) a += Ps[k] * vb[(size_t)(k * 32 + b) * 1536];
      ob[(size_t)(q * 32 + b) * 512 + h * 128 + t] = __float2bfloat16(a / sm);
    }
  }
}

// ---------------------------------------------------------------------------
// Fused decoder layer: bf16-transposed-weight coalesced GEMVs. 512 thr, grid 32.
// Identical indexing to the fp32 version; 4 bf16 (8B) per thread per k.
template<int N, int K, int RELU>
__device__ __forceinline__ void gemvT(int tid, const float* S,
                                      const bf16* __restrict__ WT,
                                      const float* __restrict__ bias,
                                      float* out, float* part)
{
  constexpr int NQ = N / 4;
  constexpr int G = 512 / NQ;
  constexpr int KP = K / G;
  const int p = tid % NQ;
  const int g = tid / NQ;
  const short4v* wp = (const short4v*)WT;
  float ax = 0.f, ay = 0.f, az = 0.f, aw = 0.f;
  const int kend = g * KP + KP;
#pragma unroll 8
  for (int k = g * KP; k < kend; ++k) {
    const float s = S[k];
    union { short4v v; bf16 h[4]; } w;
    w.v = wp[(size_t)k * NQ + p];
    ax += s * __bfloat162float(w.h[0]);
    ay += s * __bfloat162float(w.h[1]);
    az += s * __bfloat162float(w.h[2]);
    aw += s * __bfloat162float(w.h[3]);
  }
  float4 a4 = {ax, ay, az, aw};
  *(float4*)(part + g * N + 4 * p) = a4;
  __syncthreads();
#pragma unroll
  for (int n = tid; n < N; n += 512) {
    float v = bias[n];
#pragma unroll
    for (int q = 0; q < G; ++q) v += part[q * N + n];
    if (RELU) v = fmaxf(v, 0.f);
    out[n] = v;
  }
  __syncthreads();
}

#define BLOCK_LN512(V, G, B, O)                                                 \
  {                                                                             \
    float s_ = (V), ss_ = (V) * (V);                                            \
    _Pragma("unroll")                                                           \
    for (int o_ = 32; o_ > 0; o_ >>= 1) {                                       \
      s_ += __shfl_xor(s_, o_); ss_ += __shfl_xor(ss_, o_);                     \
    }                                                                           \
    if ((tid & 63) == 0) { red[tid >> 6] = s_; red2[tid >> 6] = ss_; }          \
    __syncthreads();                                                            \
    s_ = 0.f; ss_ = 0.f;                                                        \
    _Pragma("unroll")                                                           \
    for (int w_ = 0; w_ < 8; ++w_) { s_ += red[w_]; ss_ += red2[w_]; }          \
    const float mean_ = s_ * (1.f / 512.f);                                     \
    const float inv_ = rsqrtf(ss_ * (1.f / 512.f) - mean_ * mean_ + 1e-5f);     \
    O = ((V) - mean_) * inv_ * (G)[tid] + (B)[tid];                             \
    __syncthreads();                                                            \
  }

__global__ __launch_bounds__(512)
void dec_layer(const float* __restrict__ tin,          // nullptr => ones
               const float* __restrict__ kvb, int kvstride,
               const bf16* __restrict__ WvT, const float* __restrict__ bv,
               const bf16* __restrict__ WpT, const float* __restrict__ bp,
               const float* __restrict__ g1, const float* __restrict__ b1,
               const bf16* __restrict__ WqT, const float* __restrict__ bq,
               const bf16* __restrict__ WcpT, const float* __restrict__ bcp,
               const float* __restrict__ g2, const float* __restrict__ b2,
               const bf16* __restrict__ W1T, const float* __restrict__ b1f,
               const bf16* __restrict__ W2T, const float* __restrict__ b2f,
               const float* __restrict__ g3, const float* __restrict__ b3,
               const float* __restrict__ gf, const float* __restrict__ bf_,
               int dofinal, float* __restrict__ tout,
               const bf16* __restrict__ Wo1T, const float* __restrict__ ob1,
               bf16* __restrict__ o1b)
{
  __shared__ float Ts[512], Bs[512], Cs[512], F1[1024], part[2048];
  __shared__ float Ps[4][104];
  __shared__ float red[8], red2[8];
  const int r = blockIdx.x, tid = threadIdx.x;
  Ts[tid] = tin ? tin[r * 512 + tid] : 1.0f;
  __syncthreads();

  gemvT<512, 512, 0>(tid, Ts, WvT, bv, Bs, part);
  gemvT<512, 512, 0>(tid, Bs, WpT, bp, Cs, part);
  {
    const float rr = Cs[tid] + Ts[tid];
    float o;
    BLOCK_LN512(rr, g1, b1, o)
    Ts[tid] = o;
  }
  __syncthreads();

  gemvT<512, 512, 0>(tid, Ts, WqT, bq, Bs, part);

  if (tid < 256) {
    const int h = tid >> 6, lane = tid & 63;
    const float scale = 0.08838834764831845f;
    const float* Qh = Bs + h * 128;
    float s0, s1 = -3e38f;
    {
      const float* kr = kvb + (size_t)(lane * 32 + r) * kvstride + h * 128;
      float a = 0.f;
#pragma unroll 16
      for (int d = 0; d < 128; ++d) a += Qh[d] * kr[d];
      s0 = a * scale;
    }
    if (lane + 64 < 100) {
      const float* kr = kvb + (size_t)((lane + 64) * 32 + r) * kvstride + h * 128;
      float a = 0.f;
#pragma unroll 16
      for (int d = 0; d < 128; ++d) a += Qh[d] * kr[d];
      s1 = a * scale;
    }
    float mx = fmaxf(s0, s1);
#pragma unroll
    for (int o = 32; o > 0; o >>= 1) mx = fmaxf(mx, __shfl_xor(mx, o));
    const float e0 = expf(s0 - mx);
    const float e1 = (lane + 64 < 100) ? expf(s1 - mx) : 0.f;
    float sm = e0 + e1;
#pragma unroll
    for (int o = 32; o > 0; o >>= 1) sm += __shfl_xor(sm, o);
    Ps[h][lane] = e0 / sm;
    if (lane + 64 < 100) Ps[h][lane + 64] = e1 / sm;
  }
  __syncthreads();
  if (tid < 256) {
    const int h = tid >> 6, lane = tid & 63;
#pragma unroll
    for (int u = 0; u < 2; ++u) {
      const int d = lane + u * 64;
      const float* vb = kvb + 512 + h * 128 + d;
      float a = 0.f;
      for (int k = 0; k < 100; ++k) a += Ps[h][k] * vb[(size_t)(k * 32 + r) * kvstride];
      Bs[h * 128 + d] = a;
    }
  }
  __syncthreads();

  gemvT<512, 512, 0>(tid, Bs, WcpT, bcp, Cs, part);
  {
    const float rr = Cs[tid] + Ts[tid];
    float o;
    BLOCK_LN512(rr, g2, b2, o)
    Ts[tid] = o;
  }
  __syncthreads();

  gemvT<1024, 512, 1>(tid, Ts, W1T, b1f, F1, part);
  gemvT<512, 1024, 0>(tid, F1, W2T, b2f, Cs, part);
  {
    const float rr = Cs[tid] + Ts[tid];
    float o;
    BLOCK_LN512(rr, g3, b3, o)
    if (dofinal) {
      float f;
      BLOCK_LN512(o, gf, bf_, f)
      o = f;
    }
    tout[r * 512 + tid] = o;
    if (dofinal) {
      Ts[tid] = o;
      __syncthreads();
      // fused out1: row r of C(32,2048) = relu(t @ Wo1T + b); 4 outputs/thread
      const short4v* wp = (const short4v*)Wo1T;   // [512][512 bf16-quads]
      float ax = 0.f, ay = 0.f, az = 0.f, aw = 0.f;
#pragma unroll 8
      for (int k = 0; k < 512; ++k) {
        const float s = Ts[k];
        union { short4v v; bf16 h[4]; } w;
        w.v = wp[(size_t)k * 512 + tid];
        ax += s * __bfloat162float(w.h[0]);
        ay += s * __bfloat162float(w.h[1]);
        az += s * __bfloat162float(w.h[2]);
        aw += s * __bfloat162float(w.h[3]);
      }
      union { short4v v; bf16 h[4]; } u;
      u.h[0] = __float2bfloat16(fmaxf(ax + ob1[4 * tid], 0.f));
      u.h[1] = __float2bfloat16(fmaxf(ay + ob1[4 * tid + 1], 0.f));
      u.h[2] = __float2bfloat16(fmaxf(az + ob1[4 * tid + 2], 0.f));
      u.h[3] = __float2bfloat16(fmaxf(aw + ob1[4 * tid + 3], 0.f));
      *(short4v*)(o1b + (size_t)r * 2048 + 4 * tid) = u.v;
      const short4v z = {0, 0, 0, 0};
#pragma unroll
      for (int rr = r + 32; rr < 128; rr += 32)
        *(short4v*)(o1b + (size_t)rr * 2048 + 4 * tid) = z;
    }
  }
}

// ---------------------------------------------------------------------------
// out3 split-K reduce (+bias(+guard)+relu) fused with adaptive pool. grid 32.
__global__ __launch_bounds__(256)
void reduce_pool(const float* __restrict__ P, size_t pstride,
                 const float* __restrict__ bias, float* __restrict__ out)
{
  __shared__ float row[NOUT3];
  const int b = blockIdx.x, t = threadIdx.x;
  for (int n = t * 4; n < NOUT3; n += 1024) {
    const size_t o = (size_t)b * NOUT3 + n;
    float4 s = *(const float4*)(P + o);
#pragma unroll
    for (int k = 1; k < 4; ++k) {
      const float4 p = *(const float4*)(P + (size_t)k * pstride + o);
      s.x += p.x; s.y += p.y; s.z += p.z; s.w += p.w;
    }
    row[n]     = fmaxf(s.x + ((n     < FLATIN) ? bias[n]     : 0.f), 0.f);
    row[n + 1] = fmaxf(s.y + ((n + 1 < FLATIN) ? bias[n + 1] : 0.f), 0.f);
    row[n + 2] = fmaxf(s.z + ((n + 2 < FLATIN) ? bias[n + 2] : 0.f), 0.f);
    row[n + 3] = fmaxf(s.w + ((n + 3 < FLATIN) ? bias[n + 3] : 0.f), 0.f);
  }
  __syncthreads();
  for (int i = t; i < 135 * 103; i += 256) {
    const int j = i % 103, r = i / 103;
    const int rs = (r * 143) / 135, re = ((r + 1) * 143 + 134) / 135;
    const int cs = (j * 111) / 103, ce = ((j + 1) * 111 + 102) / 103;
    float s = 0.f;
    for (int rr = rs; rr < re; ++rr)
      for (int cc = cs; cc < ce; ++cc)
        s += row[rr * 111 + cc];
    out[(size_t)b * (135 * 103) + i] = s / (float)((re - rs) * (ce - cs));
  }
}

// ---------------------------------------------------------------------------
extern "C" void kernel_launch(void* const* d_in, const int* in_sizes, int n_in,
                              void* d_out, int out_size, void* d_ws, size_t ws_size,
                              hipStream_t stream)
{
  (void)in_sizes; (void)n_in; (void)out_size; (void)ws_size;

  const float* x          = (const float*)d_in[0];
  const float* fc1_w      = (const float*)d_in[1];
  const float* fc1_b      = (const float*)d_in[2];
  const float* fc2_w      = (const float*)d_in[3];
  const float* fc2_b      = (const float*)d_in[4];
  const float* fc3_w      = (const float*)d_in[5];
  const float* fc3_b      = (const float*)d_in[6];
  const float* out1_w     = (const float*)d_in[7];
  const float* out1_b     = (const float*)d_in[8];
  const float* out2_w     = (const float*)d_in[9];
  const float* out2_b     = (const float*)d_in[10];
  const float* out3_w     = (const float*)d_in[11];
  const float* out3_b     = (const float*)d_in[12];
  const float* enc_qkv_w  = (const float*)d_in[13];
  const float* enc_qkv_b  = (const float*)d_in[14];
  const float* enc_proj_w = (const float*)d_in[15];
  const float* enc_proj_b = (const float*)d_in[16];
  const float* enc_ff1_w  = (const float*)d_in[17];
  const float* enc_ff1_b  = (const float*)d_in[18];
  const float* enc_ff2_w  = (const float*)d_in[19];
  const float* enc_ff2_b  = (const float*)d_in[20];
  const float* enc_ln1_g  = (const float*)d_in[21];
  const float* enc_ln1_b  = (const float*)d_in[22];
  const float* enc_ln2_g  = (const float*)d_in[23];
  const float* enc_ln2_b  = (const float*)d_in[24];
  const float* enc_lnf_g  = (const float*)d_in[25];
  const float* enc_lnf_b  = (const float*)d_in[26];
  const float* dec_sa_qkv_w  = (const float*)d_in[27];
  const float* dec_sa_qkv_b  = (const float*)d_in[28];
  const float* dec_sa_proj_w = (const float*)d_in[29];
  const float* dec_sa_proj_b = (const float*)d_in[30];
  const float* dec_ca_qkv_w  = (const float*)d_in[31];
  const float* dec_ca_qkv_b  = (const float*)d_in[32];
  const float* dec_ca_proj_w = (const float*)d_in[33];
  const float* dec_ca_proj_b = (const float*)d_in[34];
  const float* dec_ff1_w  = (const float*)d_in[35];
  const float* dec_ff1_b  = (const float*)d_in[36];
  const float* dec_ff2_w  = (const float*)d_in[37];
  const float* dec_ff2_b  = (const float*)d_in[38];
  const float* dec_ln1_g  = (const float*)d_in[39];
  const float* dec_ln1_b  = (const float*)d_in[40];
  const float* dec_ln2_g  = (const float*)d_in[41];
  const float* dec_ln2_b  = (const float*)d_in[42];
  const float* dec_ln3_g  = (const float*)d_in[43];
  const float* dec_ln3_b  = (const float*)d_in[44];
  const float* dec_lnf_g  = (const float*)d_in[45];
  const float* dec_lnf_b  = (const float*)d_in[46];

  char* wsp = (char*)d_ws;
  size_t off = 0;
  auto alloc = [&](size_t nbytes) -> char* {
    char* p = wsp + off;
    off += (nbytes + 255) & ~(size_t)255;
    return p;
  };

  bf16* xb     = (bf16*)alloc((size_t)MPAD * KPAD1 * 2);
  bf16* Wb1    = (bf16*)alloc((size_t)4096 * KPAD1 * 2);
  bf16* Wb2    = (bf16*)alloc((size_t)2048 * 4096 * 2);
  bf16* Wb3    = (bf16*)alloc((size_t)512 * 2048 * 2);
  bf16* Wqkvb  = (bf16*)alloc((size_t)2 * 1536 * 512 * 2);
  bf16* Wprojb = (bf16*)alloc((size_t)2 * 512 * 512 * 2);
  bf16* Wff1b  = (bf16*)alloc((size_t)2 * 1024 * 512 * 2);
  bf16* Wff2b  = (bf16*)alloc((size_t)2 * 512 * 1024 * 2);
  bf16* Wkv2b  = (bf16*)alloc((size_t)2048 * 512 * 2);
  int*   nz      = (int*)alloc(ROWS * 4);
  int*   padmask = (int*)alloc(ROWS * 4);
  int*   idx     = (int*)alloc(MPAD * 4);
  int*   pos     = (int*)alloc(ROWS * 4);
  int*   cnt     = (int*)alloc(256);
  float* kvbias  = (float*)alloc(2048 * 4);
  bf16* h1c = (bf16*)alloc((size_t)MPAD * 4096 * 2);
  bf16* h2c = (bf16*)alloc((size_t)MPAD * 2048 * 2);
  float* hf  = (float*)alloc((size_t)ROWS * 512 * 4);
  bf16* hb = (bf16*)alloc((size_t)ROWS * 512 * 2);
  float* qkvbuf = (float*)alloc((size_t)ROWS * 1536 * 4);
  bf16* attnb = (bf16*)alloc((size_t)ROWS * 512 * 2);
  float* pjf  = (float*)alloc((size_t)ROWS * 512 * 4);
  bf16* f1b = (bf16*)alloc((size_t)ROWS * 1024 * 2);
  float* f2f  = (float*)alloc((size_t)ROWS * 512 * 4);
  bf16* memb = (bf16*)alloc((size_t)ROWS * 512 * 2);
  float* kv01 = (float*)alloc((size_t)ROWS * 2048 * 4);
  float* tbuf = (float*)alloc(32 * 512 * 4);
  // bf16 transposed weights (decoder + out1)
  bf16* WvT[2]  = { (bf16*)alloc(512 * 512 * 2), (bf16*)alloc(512 * 512 * 2) };
  bf16* WpT[2]  = { (bf16*)alloc(512 * 512 * 2), (bf16*)alloc(512 * 512 * 2) };
  bf16* WqT[2]  = { (bf16*)alloc(512 * 512 * 2), (bf16*)alloc(512 * 512 * 2) };
  bf16* WcpT[2] = { (bf16*)alloc(512 * 512 * 2), (bf16*)alloc(512 * 512 * 2) };
  bf16* W1T[2]  = { (bf16*)alloc(512 * 1024 * 2), (bf16*)alloc(512 * 1024 * 2) };
  bf16* W2T[2]  = { (bf16*)alloc(1024 * 512 * 2), (bf16*)alloc(1024 * 512 * 2) };
  bf16* Wo1T    = (bf16*)alloc((size_t)512 * 2048 * 2);
  float* fcP  = (float*)alloc((size_t)4 * MPAD * 4096 * 4);   // 218 MB
  float* encP = (float*)alloc((size_t)2 * ROWS * 1536 * 4);   // aliases

  float* outP = fcP;                                           // <=33 MB
  bf16* o1b  = (bf16*)((char*)encP + ((size_t)20 << 20));
  bf16* o2b  = (bf16*)((char*)encP + ((size_t)22 << 20));

  const size_t psF1 = (size_t)MPAD * 4096;
  const size_t psF2 = (size_t)MPAD * 2048;
  const size_t psF3 = (size_t)MPAD * 512;

  // ---- phase 0: merged prep (conv_x | cvt | fc1 cvt | transpose), compact --
  {
    PrepArgs pa;
    pa.x = x; pa.xb = xb; pa.nz = nz; pa.nConv = ROWS + 1;
    const float* srcs[8] = { enc_qkv_w, enc_proj_w, enc_ff1_w, enc_ff2_w,
                             dec_ca_qkv_w + (size_t)512 * 512,
                             dec_ca_qkv_w + (size_t)(1536 + 512) * 512,
                             fc2_w, fc3_w };
    bf16* dsts[8] = { Wqkvb, Wprojb, Wff1b, Wff2b,
                      Wkv2b, Wkv2b + (size_t)1024 * 512, Wb2, Wb3 };
    const int counts[8] = { 2*1536*512, 2*512*512, 2*1024*512, 2*512*1024,
                            1024*512, 1024*512, 2048*4096, 512*2048 };
    int c = 0;
    for (int i = 0; i < 8; ++i) { pa.cv.src[i] = srcs[i]; pa.cv.dst[i] = dsts[i];
                                  pa.cv.cum[i] = c; c += counts[i] >> 11; }
    pa.nCvt = c;
    pa.fc1w = fc1_w; pa.wb1 = Wb1; pa.nFc1 = 4096;
    const float* tsr[13];
    bf16* tds[13];
    int R[13], C[13];
    int n = 0;
    for (int L = 0; L < 2; ++L) {
      tsr[n] = dec_sa_qkv_w + (size_t)L * 1536 * 512 + (size_t)1024 * 512;
      tds[n] = WvT[L]; R[n] = 512; C[n] = 512; ++n;
      tsr[n] = dec_sa_proj_w + (size_t)L * 512 * 512;
      tds[n] = WpT[L]; R[n] = 512; C[n] = 512; ++n;
      tsr[n] = dec_ca_qkv_w + (size_t)L * 1536 * 512;
      tds[n] = WqT[L]; R[n] = 512; C[n] = 512; ++n;
      tsr[n] = dec_ca_proj_w + (size_t)L * 512 * 512;
      tds[n] = WcpT[L]; R[n] = 512; C[n] = 512; ++n;
      tsr[n] = dec_ff1_w + (size_t)L * 1024 * 512;
      tds[n] = W1T[L]; R[n] = 1024; C[n] = 512; ++n;
      tsr[n] = dec_ff2_w + (size_t)L * 512 * 1024;
      tds[n] = W2T[L]; R[n] = 512; C[n] = 1024; ++n;
    }
    tsr[n] = out1_w; tds[n] = Wo1T; R[n] = 2048; C[n] = 512; ++n;
    int tc = 0;
    for (int i = 0; i < 13; ++i) {
      pa.tr.src[i] = tsr[i]; pa.tr.dst[i] = tds[i];
      pa.tr.R[i] = R[i]; pa.tr.C[i] = C[i];
      pa.tr.cum[i] = tc; tc += (R[i] >> 6) * (C[i] >> 6);
    }
    prep_kernel<<<pa.nConv + pa.nCvt + pa.nFc1 + tc, 256, 0, stream>>>(pa);
  }
  compact_kernel<<<1, 256, 0, stream>>>(nz, idx, pos, cnt, padmask,
                                        dec_ca_qkv_b, kvbias);

  // ---- phase 1: input MLP (split-K) ----
  gemm_bf16<1><<<26 * 32 * 2, 256, 0, stream>>>(xb, Wb1, idx, cnt, fcP,
      KPAD1, 4096, 26, 2, psF1);
  reduce_kernel<1, 0, 1><<<dim3(4, MPAD), 256, 0, stream>>>(fcP, psF1, 2,
      fc1_b, nullptr, h1c, 4096, cnt);
  gemm_bf16<0><<<26 * 16 * 4, 256, 0, stream>>>(h1c, Wb2, nullptr, cnt, fcP,
      4096, 2048, 26, 4, psF2);
  reduce_kernel<1, 0, 1><<<dim3(2, MPAD), 256, 0, stream>>>(fcP, psF2, 4,
      fc2_b, nullptr, h2c, 2048, cnt);
  gemm_bf16<0><<<26 * 4 * 4, 256, 0, stream>>>(h2c, Wb3, nullptr, cnt, fcP,
      2048, 512, 26, 4, psF3);
  scatter_pe_reduce<<<ROWS, 256, 0, stream>>>(fcP, psF3, 4, pos, fc3_b, hf, hb);

  // ---- phase 2: encoder ----
  for (int L = 0; L < 2; ++L) {
    gemm_direct<0, 1, 0><<<25 * 12, 256, 0, stream>>>(hb, Wqkvb + (size_t)L * 1536 * 512,
        enc_qkv_b + L * 1536, qkvbuf, nullptr, 512, 1536, 25);
    enc_attn_kernel<<<dim3(128, 25), 256, 0, stream>>>(qkvbuf, padmask, attnb);
    gemm_direct<0, 1, 0><<<25 * 4, 256, 0, stream>>>(attnb, Wprojb + (size_t)L * 512 * 512,
        enc_proj_b + L * 512, pjf, nullptr, 512, 512, 25);
    ln_kernel<<<ROWS, 256, 0, stream>>>(hf, pjf, enc_ln1_g + L * 512, enc_ln1_b + L * 512,
        nullptr, nullptr, 0, hf, hb);
    gemm_direct<1, 0, 1><<<25 * 8, 256, 0, stream>>>(hb, Wff1b + (size_t)L * 1024 * 512,
        enc_ff1_b + L * 1024, nullptr, f1b, 512, 1024, 25);
    gemm_direct<0, 1, 0><<<25 * 4, 256, 0, stream>>>(f1b, Wff2b + (size_t)L * 512 * 1024,
        enc_ff2_b + L * 512, f2f, nullptr, 1024, 512, 25);
    if (L == 0) {
      ln_kernel<<<ROWS, 256, 0, stream>>>(hf, f2f, enc_ln2_g, enc_ln2_b,
          nullptr, nullptr, 0, hf, hb);
    } else {
      ln_kernel<<<ROWS, 256, 0, stream>>>(hf, f2f, enc_ln2_g + 512, enc_ln2_b + 512,
          enc_lnf_g, enc_lnf_b, 1, nullptr, memb);
    }
  }

  // ---- decoder KV (both layers, one GEMM) ----
  gemm_direct<0, 1, 0><<<25 * 16, 256, 0, stream>>>(memb, Wkv2b, kvbias,
      kv01, nullptr, 512, 2048, 25);

  // ---- phase 3: fused decoder layers (bf16 weights; out1 fused into L1) ----
  for (int L = 0; L < 2; ++L) {
    dec_layer<<<32, 512, 0, stream>>>(
        (L == 0) ? nullptr : tbuf,
        kv01 + (size_t)L * 1024, 2048,
        WvT[L], dec_sa_qkv_b + L * 1536 + 1024,
        WpT[L], dec_sa_proj_b + L * 512,
        dec_ln1_g + L * 512, dec_ln1_b + L * 512,
        WqT[L], dec_ca_qkv_b + L * 1536,
        WcpT[L], dec_ca_proj_b + L * 512,
        dec_ln2_g + L * 512, dec_ln2_b + L * 512,
        W1T[L], dec_ff1_b + L * 1024,
        W2T[L], dec_ff2_b + L * 512,
        dec_ln3_g + L * 512, dec_ln3_b + L * 512,
        dec_lnf_g, dec_lnf_b, (L == 1) ? 1 : 0, tbuf,
        Wo1T, out1_b, o1b);
  }

  // ---- phase 4: output MLP (fp32-weight GEMMs, conversion fused) ----
  gemm_w32<<<32 * 4, 256, 0, stream>>>(o1b, out2_w, outP,
      2048, 4096, 4, (size_t)128 * 4096, 4096);
  reduce_kernel<1, 0, 1><<<dim3(4, 128), 256, 0, stream>>>(outP, (size_t)128 * 4096, 4,
      out2_b, nullptr, o2b, 4096, nullptr);
  gemm_w32<<<125 * 4, 256, 0, stream>>>(o2b, out3_w, outP,
      4096, NOUT3, 4, (size_t)128 * NOUT3, FLATIN);
  reduce_pool<<<32, 256, 0, stream>>>(outP, (size_t)128 * NOUT3, out3_b, (float*)d_out);
}

// Round 18
// 1296.300 us; speedup vs baseline: 1.1911x; 1.0036x over previous
//
#include <hip/hip_runtime.h>
#include <hip/hip_bf16.h>

// ---------------------------------------------------------------------------
#define SEQ   100
#define BATCH 32
#define FLATIN 15873
#define KPAD1  16384
#define ROWS   3200
#define MPAD   3328
#define NOUT3  16000

typedef __attribute__((ext_vector_type(8))) short short8;
typedef __attribute__((ext_vector_type(4))) short short4v;
typedef __attribute__((ext_vector_type(4))) float f32x4;
typedef __hip_bfloat16 bf16;

__device__ __forceinline__ void gload_lds16(const void* g, void* l) {
  __builtin_amdgcn_global_load_lds((const __attribute__((address_space(1))) void*)g,
                                   (__attribute__((address_space(3))) void*)l, 16, 0, 0);
}

// bijective XCD chunk swizzle (m204)
__device__ __forceinline__ int xcd_swizzle(int id, int nwg) {
  const int q = nwg >> 3, r = nwg & 7;
  const int x = id & 7, p = id >> 3;
  return (x < r ? x * (q + 1) : r * (q + 1) + (x - r) * q) + p;
}

// ---------------------------------------------------------------------------
// Shared GEMM body: stage 128x64 A/B tiles (both-sides chunk swizzle), MFMA.
#define GEMM_BODY(KBEG, KEND)                                                   \
  const int tid  = threadIdx.x;                                                 \
  const int lane = tid & 63;                                                    \
  const int wid  = tid >> 6;                                                    \
  const int wr = (wid >> 1) << 6;                                               \
  const int wc = (wid & 1) << 6;                                                \
  f32x4 acc[4][4];                                                              \
  _Pragma("unroll") for (int i = 0; i < 4; ++i)                                 \
  _Pragma("unroll") for (int j = 0; j < 4; ++j)                                 \
      acc[i][j] = (f32x4){0.f, 0.f, 0.f, 0.f};                                  \
  const int srow = (wid << 3) + (lane >> 3);                                    \
  const int scs  = lane & 7;                                                    \
  const int gcol = ((scs ^ (srow & 7)) << 3);                                   \
  const bf16* arow[4];                                                          \
  const bf16* brow[4];                                                          \
  _Pragma("unroll") for (int j = 0; j < 4; ++j) {                               \
    const int row = (j << 5) + srow;                                            \
    const int gr = GATHER ? idx[m0 + row] : (m0 + row);                         \
    arow[j] = A + (size_t)gr * K + gcol;                                        \
    brow[j] = W + (size_t)(n0 + row) * K + gcol;                                \
  }                                                                             \
  for (int k0 = (KBEG); k0 < (KEND); k0 += 64) {                                \
    __syncthreads();                                                            \
    _Pragma("unroll") for (int j = 0; j < 4; ++j) {                             \
      short* la = As + (((j << 2) + wid) << 9);                                 \
      short* lb = Bs + (((j << 2) + wid) << 9);                                 \
      gload_lds16(arow[j] + k0, la);                                            \
      gload_lds16(brow[j] + k0, lb);                                            \
    }                                                                           \
    __syncthreads();                                                            \
    _Pragma("unroll") for (int kk = 0; kk < 2; ++kk) {                          \
      short8 af[4], bfv[4];                                                     \
      _Pragma("unroll") for (int i = 0; i < 4; ++i) {                           \
        const int mr = wr + (i << 4) + (lane & 15);                             \
        const int cg = (kk << 2) + (lane >> 4);                                 \
        af[i]  = *(const short8*)(As + mr * 64 + ((cg ^ (mr & 7)) << 3));       \
        const int nr = wc + (i << 4) + (lane & 15);                             \
        bfv[i] = *(const short8*)(Bs + nr * 64 + ((cg ^ (nr & 7)) << 3));       \
      }                                                                         \
      _Pragma("unroll") for (int i = 0; i < 4; ++i)                             \
      _Pragma("unroll") for (int j = 0; j < 4; ++j)                             \
          acc[i][j] = __builtin_amdgcn_mfma_f32_16x16x32_bf16(af[i], bfv[j],    \
                                                              acc[i][j], 0,0,0);\
    }                                                                           \
  }

// Split-K partial-output GEMM. mt-minor linearization.
template<int GATHER>
__global__ __launch_bounds__(256)
void gemm_bf16(const bf16* __restrict__ A, const bf16* __restrict__ W,
               const int* __restrict__ idx, const int* __restrict__ cnt,
               float* __restrict__ P,
               int K, int ldc, int mtiles, int ksl, size_t pstride)
{
  __shared__ __align__(16) short lds[16384];
  short* As = lds;
  short* Bs = lds + 8192;
  const int wg = xcd_swizzle(blockIdx.x, gridDim.x);
  const int mt = wg % mtiles;
  const int g  = wg / mtiles;
  const int nt = g / ksl;
  const int ks = g % ksl;
  const int m0 = mt << 7;
  const int n0 = nt << 7;
  if (cnt && m0 >= cnt[0]) return;
  const int Klen = K / ksl;
  const int kbeg = ks * Klen;

  GEMM_BODY(kbeg, kbeg + Klen)

  float* Pout = P + (size_t)ks * pstride;
  const int fr = lane & 15, fq = lane >> 4;
#pragma unroll
  for (int j = 0; j < 4; ++j) {
    const int n = n0 + wc + (j << 4) + fr;
#pragma unroll
    for (int i = 0; i < 4; ++i)
#pragma unroll
      for (int r = 0; r < 4; ++r) {
        const int m = m0 + wr + (i << 4) + (fq << 2) + r;
        Pout[(size_t)m * ldc + n] = acc[i][j][r];
      }
  }
}

// Direct GEMM with fused bias/relu epilogue
template<int RELU, int OF32, int OB16>
__global__ __launch_bounds__(256)
void gemm_direct(const bf16* __restrict__ A, const bf16* __restrict__ W,
                 const float* __restrict__ bias, float* __restrict__ Cf,
                 bf16* __restrict__ Cb, int K, int ldc, int mtiles)
{
  __shared__ __align__(16) short lds[16384];
  short* As = lds;
  short* Bs = lds + 8192;
  const int GATHER = 0;
  const int* idx = nullptr;
  const int wg = xcd_swizzle(blockIdx.x, gridDim.x);
  const int m0 = (wg % mtiles) << 7;
  const int n0 = (wg / mtiles) << 7;

  GEMM_BODY(0, K)

  const int fr = lane & 15, fq = lane >> 4;
#pragma unroll
  for (int j = 0; j < 4; ++j) {
    const int n = n0 + wc + (j << 4) + fr;
    const float bb = bias[n];
#pragma unroll
    for (int i = 0; i < 4; ++i)
#pragma unroll
      for (int r = 0; r < 4; ++r) {
        const int m = m0 + wr + (i << 4) + (fq << 2) + r;
        float v = acc[i][j][r] + bb;
        if (RELU) v = fmaxf(v, 0.f);
        if (OF32) Cf[(size_t)m * ldc + n] = v;
        if (OB16) Cb[(size_t)m * ldc + n] = __float2bfloat16(v);
      }
  }
}

// ---------------------------------------------------------------------------
// Split-K GEMM with fp32 B-side (conversion fused into staging; rule #21:
// inverse-swizzled write + swizzled read). B rows clamped to wrows-1.
__global__ __launch_bounds__(256)
void gemm_w32(const bf16* __restrict__ A, const float* __restrict__ W32,
              float* __restrict__ P, int K, int ldc, int ksl, size_t pstride,
              int wrows)
{
  __shared__ __align__(16) short lds[16384];
  short* As = lds;
  short* Bs = lds + 8192;
  const int wg = xcd_swizzle(blockIdx.x, gridDim.x);
  const int nt = wg / ksl;
  const int ks = wg % ksl;
  const int m0 = 0;
  const int n0 = nt << 7;
  const int Klen = K / ksl;
  const int kbeg = ks * Klen;
  const int kend = kbeg + Klen;

  const int tid  = threadIdx.x;
  const int lane = tid & 63;
  const int wid  = tid >> 6;
  const int wr = (wid >> 1) << 6;
  const int wc = (wid & 1) << 6;

  f32x4 acc[4][4];
#pragma unroll
  for (int i = 0; i < 4; ++i)
#pragma unroll
    for (int j = 0; j < 4; ++j) acc[i][j] = (f32x4){0.f, 0.f, 0.f, 0.f};

  const int srow = (wid << 3) + (lane >> 3);
  const int scs  = lane & 7;
  const int gcol = ((scs ^ (srow & 7)) << 3);

  const bf16* arow[4];
#pragma unroll
  for (int j = 0; j < 4; ++j)
    arow[j] = A + (size_t)(m0 + (j << 5) + srow) * K + gcol;

  const float* wsrc[4];
  int bslot[4];
#pragma unroll
  for (int i = 0; i < 4; ++i) {
    const int q = (i << 8) + tid;
    const int row = q >> 3, c = q & 7;
    const int wrow = min(n0 + row, wrows - 1);
    wsrc[i] = W32 + (size_t)wrow * K + (c << 3);
    bslot[i] = row * 64 + ((c ^ (row & 7)) << 3);
  }

  for (int k0 = kbeg; k0 < kend; k0 += 64) {
    __syncthreads();
#pragma unroll
    for (int j = 0; j < 4; ++j)
      gload_lds16(arow[j] + k0, As + (((j << 2) + wid) << 9));
#pragma unroll
    for (int i = 0; i < 4; ++i) {
      const float4 w0 = *(const float4*)(wsrc[i] + k0);
      const float4 w1 = *(const float4*)(wsrc[i] + k0 + 4);
      union { short8 v; bf16 h[8]; } pk;
      pk.h[0] = __float2bfloat16(w0.x); pk.h[1] = __float2bfloat16(w0.y);
      pk.h[2] = __float2bfloat16(w0.z); pk.h[3] = __float2bfloat16(w0.w);
      pk.h[4] = __float2bfloat16(w1.x); pk.h[5] = __float2bfloat16(w1.y);
      pk.h[6] = __float2bfloat16(w1.z); pk.h[7] = __float2bfloat16(w1.w);
      *(short8*)(Bs + bslot[i]) = pk.v;
    }
    __syncthreads();
#pragma unroll
    for (int kk = 0; kk < 2; ++kk) {
      short8 af[4], bfv[4];
#pragma unroll
      for (int i = 0; i < 4; ++i) {
        const int mr = wr + (i << 4) + (lane & 15);
        const int cg = (kk << 2) + (lane >> 4);
        af[i]  = *(const short8*)(As + mr * 64 + ((cg ^ (mr & 7)) << 3));
        const int nr = wc + (i << 4) + (lane & 15);
        bfv[i] = *(const short8*)(Bs + nr * 64 + ((cg ^ (nr & 7)) << 3));
      }
#pragma unroll
      for (int i = 0; i < 4; ++i)
#pragma unroll
        for (int j = 0; j < 4; ++j)
          acc[i][j] = __builtin_amdgcn_mfma_f32_16x16x32_bf16(af[i], bfv[j], acc[i][j], 0, 0, 0);
    }
  }

  float* Pout = P + (size_t)ks * pstride;
  const int fr = lane & 15, fq = lane >> 4;
#pragma unroll
  for (int j = 0; j < 4; ++j) {
    const int n = n0 + wc + (j << 4) + fr;
#pragma unroll
    for (int i = 0; i < 4; ++i)
#pragma unroll
      for (int r = 0; r < 4; ++r) {
        const int m = m0 + wr + (i << 4) + (fq << 2) + r;
        Pout[(size_t)m * ldc + n] = acc[i][j][r];
      }
  }
}

// ---------------------------------------------------------------------------
// Split-K reduce: C = sum_ks P[ks] + bias [, relu]
template<int RELU, int OF32, int OB16>
__global__ __launch_bounds__(256)
void reduce_kernel(const float* __restrict__ P, size_t pstride, int ksl,
                   const float* __restrict__ bias, float* __restrict__ Cf,
                   bf16* __restrict__ Cb, int N, const int* __restrict__ cnt)
{
  const int row = blockIdx.y;
  if (cnt) { const int cp = (cnt[0] + 127) & ~127; if (row >= cp) return; }
  const int n = (blockIdx.x * 256 + threadIdx.x) * 4;
  if (n >= N) return;
  const size_t o = (size_t)row * N + n;
  const float4 b4 = *(const float4*)(bias + n);
  float4 s = *(const float4*)(P + o);
  for (int k = 1; k < ksl; ++k) {
    const float4 p = *(const float4*)(P + (size_t)k * pstride + o);
    s.x += p.x; s.y += p.y; s.z += p.z; s.w += p.w;
  }
  s.x += b4.x; s.y += b4.y; s.z += b4.z; s.w += b4.w;
  if (RELU) {
    s.x = fmaxf(s.x, 0.f); s.y = fmaxf(s.y, 0.f);
    s.z = fmaxf(s.z, 0.f); s.w = fmaxf(s.w, 0.f);
  }
  if (OF32) *(float4*)(Cf + o) = s;
  if (OB16) {
    union { short4v v; bf16 h[4]; } u;
    u.h[0] = __float2bfloat16(s.x);
    u.h[1] = __float2bfloat16(s.y);
    u.h[2] = __float2bfloat16(s.z);
    u.h[3] = __float2bfloat16(s.w);
    *(short4v*)(Cb + o) = u.v;
  }
}

// Compaction + padding mask + decoder-KV bias concat (single block)
__global__ __launch_bounds__(256)
void compact_kernel(const int* __restrict__ nz, int* __restrict__ idx,
                    int* __restrict__ pos, int* __restrict__ cnt,
                    int* __restrict__ pad,
                    const float* __restrict__ dkvb, float* __restrict__ kvbias)
{
  __shared__ int wsum[4];
  __shared__ int total;
  const int t = threadIdx.x;
  int loc[13];
  int c = 0;
#pragma unroll
  for (int i = 0; i < 13; ++i) {
    const int m = t * 13 + i;
    loc[i] = (m < ROWS) ? nz[m] : 0;
    c += loc[i];
  }
  int v = c;
#pragma unroll
  for (int o = 1; o < 64; o <<= 1) {
    const int u = __shfl_up(v, o);
    if ((t & 63) >= o) v += u;
  }
  if ((t & 63) == 63) wsum[t >> 6] = v;
  __syncthreads();
  int wbase = 0;
  for (int w = 0; w < (t >> 6); ++w) wbase += wsum[w];
  int p = wbase + v - c;
#pragma unroll
  for (int i = 0; i < 13; ++i) {
    const int m = t * 13 + i;
    if (m < ROWS) {
      if (loc[i]) { idx[p] = m; pos[m] = p; ++p; }
      else pos[m] = -1;
    }
  }
  if (t == 255) total = p;
  __syncthreads();
  const int count = total;
  if (t == 0) cnt[0] = count + 1;
  for (int i = count + t; i < MPAD; i += 256) idx[i] = ROWS;
  for (int m = t; m < ROWS; m += 256) if (pos[m] < 0) pos[m] = count;
  if (t < 32) {
    int any = 0;
    for (int s = 99; s >= 0; --s) {
      any |= nz[t * 100 + s];
      pad[t * 100 + s] = (s > 0 && !any) ? 1 : 0;
    }
  }
#pragma unroll
  for (int i = t; i < 2048; i += 256) {
    const int L = i >> 10, j = i & 1023;
    kvbias[i] = dkvb[L * 1536 + 512 + j];
  }
}

// ---------------------------------------------------------------------------
// Merged prep kernel: conv_x | multi-cvt | fc1 padded cvt | multi transpose
// (transpose emits bf16 decoder/out1 weights).
struct CvtArgs {
  const float* src[8];
  bf16* dst[8];
  int cum[8];
};
struct TrArgs {
  const float* src[13];
  bf16* dst[13];
  int R[13], C[13], cum[13];
};
struct PrepArgs {
  CvtArgs cv;
  TrArgs tr;
  const float* x;
  bf16* xb;
  int* nz;
  const float* fc1w;
  bf16* wb1;
  int nConv, nCvt, nFc1;   // block counts of first three partitions
};
__global__ __launch_bounds__(256)
void prep_kernel(PrepArgs a)
{
  __shared__ float tbuf[64][65];
  __shared__ int sred[4];
  const int bid0 = blockIdx.x;
  if (bid0 < a.nConv) {
    const int m = bid0;                    // 0..ROWS
    const int t = threadIdx.x;
    bf16* dst = a.xb + (size_t)m * KPAD1;
    if (m == ROWS) {
      const __hip_bfloat162 z2 = {__float2bfloat16(0.f), __float2bfloat16(0.f)};
      for (int c = t; c < (KPAD1 >> 1); c += 256) *(__hip_bfloat162*)(dst + 2 * c) = z2;
      return;
    }
    const float* src = a.x + (size_t)m * FLATIN;
    int any = 0;
    for (int c = t; c < (KPAD1 >> 1); c += 256) {
      const int c0 = 2 * c;
      const float v0 = (c0 < FLATIN) ? src[c0] : 0.f;
      const float v1 = (c0 + 1 < FLATIN) ? src[c0 + 1] : 0.f;
      any |= (v0 != 0.f) | (v1 != 0.f);
      __hip_bfloat162 pr;
      pr.x = __float2bfloat16(v0);
      pr.y = __float2bfloat16(v1);
      *(__hip_bfloat162*)(dst + c0) = pr;
    }
    any = __any(any) ? 1 : 0;
    if ((t & 63) == 0) sred[t >> 6] = any;
    __syncthreads();
    if (t == 0) a.nz[m] = sred[0] | sred[1] | sred[2] | sred[3];
  } else if (bid0 < a.nConv + a.nCvt) {
    const int bid = bid0 - a.nConv;
    int seg = 0;
#pragma unroll
    for (int i = 1; i < 8; ++i) if (bid >= a.cv.cum[i]) seg = i;
    const size_t e0 = ((size_t)(bid - a.cv.cum[seg]) << 11) + (threadIdx.x << 3);
    const float4 v0 = *(const float4*)(a.cv.src[seg] + e0);
    const float4 v1 = *(const float4*)(a.cv.src[seg] + e0 + 4);
    union { short8 v; bf16 h[8]; } pk;
    pk.h[0] = __float2bfloat16(v0.x); pk.h[1] = __float2bfloat16(v0.y);
    pk.h[2] = __float2bfloat16(v0.z); pk.h[3] = __float2bfloat16(v0.w);
    pk.h[4] = __float2bfloat16(v1.x); pk.h[5] = __float2bfloat16(v1.y);
    pk.h[6] = __float2bfloat16(v1.z); pk.h[7] = __float2bfloat16(v1.w);
    *(short8*)(a.cv.dst[seg] + e0) = pk.v;
  } else if (bid0 < a.nConv + a.nCvt + a.nFc1) {
    const int r = bid0 - a.nConv - a.nCvt;  // 0..4095
    const float* src = a.fc1w + (size_t)r * FLATIN;
    bf16* dst = a.wb1 + (size_t)r * KPAD1;
#pragma unroll
    for (int u = 0; u < KPAD1 / 2048; ++u) {
      const int c0 = u * 2048 + threadIdx.x * 8;
      union { short8 v; bf16 h[8]; } pk;
      if (c0 + 8 <= FLATIN) {
        const float4 p = *(const float4*)(src + c0);
        const float4 q = *(const float4*)(src + c0 + 4);
        pk.h[0] = __float2bfloat16(p.x); pk.h[1] = __float2bfloat16(p.y);
        pk.h[2] = __float2bfloat16(p.z); pk.h[3] = __float2bfloat16(p.w);
        pk.h[4] = __float2bfloat16(q.x); pk.h[5] = __float2bfloat16(q.y);
        pk.h[6] = __float2bfloat16(q.z); pk.h[7] = __float2bfloat16(q.w);
      } else {
#pragma unroll
        for (int i = 0; i < 8; ++i)
          pk.h[i] = __float2bfloat16((c0 + i < FLATIN) ? src[c0 + i] : 0.f);
      }
      *(short8*)(dst + c0) = pk.v;
    }
  } else {
    const int bid = bid0 - a.nConv - a.nCvt - a.nFc1;
    int seg = 0;
#pragma unroll
    for (int i = 1; i < 13; ++i) if (bid >= a.tr.cum[i]) seg = i;
    const int local = bid - a.tr.cum[seg];
    const int R = a.tr.R[seg], C = a.tr.C[seg];
    const int tilesC = C >> 6;
    const int r0 = (local / tilesC) << 6;
    const int c0 = (local % tilesC) << 6;
    const int tx = threadIdx.x & 63, ty = threadIdx.x >> 6;
    const float* s = a.tr.src[seg];
    bf16* d = a.tr.dst[seg];
#pragma unroll
    for (int i = 0; i < 16; ++i) {
      const int rr = (ty << 4) + i;
      tbuf[rr][tx] = s[(size_t)(r0 + rr) * C + c0 + tx];
    }
    __syncthreads();
#pragma unroll
    for (int i = 0; i < 16; ++i) {
      const int cc = (ty << 4) + i;
      d[(size_t)(c0 + cc) * R + r0 + tx] = __float2bfloat16(tbuf[tx][cc]);
    }
  }
}

// fc3 reduce + bias + relu + scatter + inline PE
__global__ __launch_bounds__(256)
void scatter_pe_reduce(const float* __restrict__ P, size_t pstride, int ksl,
                       const int* __restrict__ pos, const float* __restrict__ bias,
                       float* __restrict__ hf, bf16* __restrict__ hb)
{
  const int m = blockIdx.x;
  const int s = m % 100, b = m / 100;
  const int src = pos[m];
  const int t = threadIdx.x;
  const size_t sb = (size_t)src * 512;
  const size_t db = (size_t)(s * 32 + b) * 512;
#pragma unroll
  for (int u = 0; u < 2; ++u) {
    const int d = t + u * 256;
    float v = bias[d];
    for (int k = 0; k < ksl; ++k) v += P[(size_t)k * pstride + sb + d];
    const float div = expf((float)(2 * (d >> 1)) * (-9.210340371976184f / 512.f));
    const float arg = (float)s * div;
    const float pe = (d & 1) ? cosf(arg) : sinf(arg);
    v = fmaxf(v, 0.f) + pe;
    hf[db + d] = v;
    hb[db + d] = __float2bfloat16(v);
  }
}

// ---------------------------------------------------------------------------
// LayerNorm over D=512 (+ optional second, final LN fused)
__global__ __launch_bounds__(256)
void ln_kernel(const float* __restrict__ x, const float* __restrict__ res,
               const float* __restrict__ g, const float* __restrict__ bta,
               const float* __restrict__ gf, const float* __restrict__ bf_,
               int dofinal, float* __restrict__ y, bf16* __restrict__ yb)
{
  __shared__ float rs[4], rss[4];
  const int row = blockIdx.x;
  const int t = threadIdx.x;
  const size_t base = (size_t)row * 512;
  float v0 = x[base + t];
  float v1 = x[base + t + 256];
  if (res) { v0 += res[base + t]; v1 += res[base + t + 256]; }
  float o0, o1;
#pragma unroll
  for (int pass = 0; pass < 2; ++pass) {
    float s = v0 + v1, ss = v0 * v0 + v1 * v1;
#pragma unroll
    for (int o = 32; o > 0; o >>= 1) { s += __shfl_xor(s, o); ss += __shfl_xor(ss, o); }
    if ((t & 63) == 0) { rs[t >> 6] = s; rss[t >> 6] = ss; }
    __syncthreads();
    s = rs[0] + rs[1] + rs[2] + rs[3];
    ss = rss[0] + rss[1] + rss[2] + rss[3];
    __syncthreads();
    const float mean = s * (1.f / 512.f);
    const float var = ss * (1.f / 512.f) - mean * mean;
    const float inv = rsqrtf(var + 1e-5f);
    const float* gg = (pass == 0) ? g : gf;
    const float* bb = (pass == 0) ? bta : bf_;
    o0 = (v0 - mean) * inv * gg[t] + bb[t];
    o1 = (v1 - mean) * inv * gg[t + 256] + bb[t + 256];
    if (pass == 1 || !dofinal) break;
    v0 = o0; v1 = o1;
  }
  if (y) {
    y[base + t] = o0;
    y[base + t + 256] = o1;
  }
  if (yb) {
    yb[base + t] = __float2bfloat16(o0);
    yb[base + t + 256] = __float2bfloat16(o1);
  }
}

// ---------------------------------------------------------------------------
// Encoder self-attention. grid (128 bh, 13 qg): 8 q's per block (uniform break
// past q=99). 1664 blocks = 6.5/CU, half the K-staging of the 4-q variant.
__global__ __launch_bounds__(256)
void enc_attn_kernel(const float* __restrict__ qkv, const int* __restrict__ pad,
                     bf16* __restrict__ ob)
{
  __shared__ float Ks[100][129];
  __shared__ float Qs[128];
  __shared__ float Ps[100];
  __shared__ float red[4];
  const int bh = blockIdx.x;
  const int b = bh >> 2, h = bh & 3;
  const int q0 = blockIdx.y * 8;
  const int t = threadIdx.x;
  for (int i = t; i < 12800; i += 256) {
    const int s = i >> 7, d = i & 127;
    Ks[s][d] = qkv[(size_t)(s * 32 + b) * 1536 + 512 + h * 128 + d];
  }
  const int masked = (t < 100) ? pad[b * 100 + t] : 0;
  const float scale = 0.08838834764831845f;
  for (int qi = 0; qi < 8; ++qi) {
    const int q = q0 + qi;
    if (q >= SEQ) break;                   // uniform across block
    __syncthreads();
    if (t < 128) Qs[t] = qkv[(size_t)(q * 32 + b) * 1536 + h * 128 + t];
    __syncthreads();
    float sc = -3e38f;
    if (t < 100) {
      const float* kr = &Ks[t][0];
      float a = 0.f;
#pragma unroll 16
      for (int d = 0; d < 128; ++d) a += Qs[d] * kr[d];
      sc = masked ? -1e9f : (a * scale);
    }
    float mx = sc;
#pragma unroll
    for (int o = 32; o > 0; o >>= 1) mx = fmaxf(mx, __shfl_xor(mx, o));
    if ((t & 63) == 0) red[t >> 6] = mx;
    __syncthreads();
    mx = fmaxf(fmaxf(red[0], red[1]), fmaxf(red[2], red[3]));
    const float e = (t < 100) ? expf(sc - mx) : 0.f;
    float sm = e;
#pragma unroll
    for (int o = 32; o > 0; o >>= 1) sm += __shfl_xor(sm, o);
    __syncthreads();
    if ((t & 63) == 0) red[t >> 6] = sm;
    __syncthreads();
    sm = red[0] + red[1] + red[2] + red[3];
    if (t < 100) Ps[t] = e;
    __syncthreads();
    if (t < 128) {
      float a = 0.f;
      const float* vb = qkv + 1024 + h * 128 + t;
      for (int k = 0; k < 100; ++k) a += Ps[k] * vb[(size_t)(k * 32 + b) * 1536];
      ob[(size_t)(q * 32 + b) * 512 + h * 128 + t] = __float2bfloat16(a / sm);
    }
  }
}

// ---------------------------------------------------------------------------
// Fused decoder layer: bf16-transposed-weight coalesced GEMVs. 512 thr, grid 32.
template<int N, int K, int RELU>
__device__ __forceinline__ void gemvT(int tid, const float* S,
                                      const bf16* __restrict__ WT,
                                      const float* __restrict__ bias,
                                      float* out, float* part)
{
  constexpr int NQ = N / 4;
  constexpr int G = 512 / NQ;
  constexpr int KP = K / G;
  const int p = tid % NQ;
  const int g = tid / NQ;
  const short4v* wp = (const short4v*)WT;
  float ax = 0.f, ay = 0.f, az = 0.f, aw = 0.f;
  const int kend = g * KP + KP;
#pragma unroll 8
  for (int k = g * KP; k < kend; ++k) {
    const float s = S[k];
    union { short4v v; bf16 h[4]; } w;
    w.v = wp[(size_t)k * NQ + p];
    ax += s * __bfloat162float(w.h[0]);
    ay += s * __bfloat162float(w.h[1]);
    az += s * __bfloat162float(w.h[2]);
    aw += s * __bfloat162float(w.h[3]);
  }
  float4 a4 = {ax, ay, az, aw};
  *(float4*)(part + g * N + 4 * p) = a4;
  __syncthreads();
#pragma unroll
  for (int n = tid; n < N; n += 512) {
    float v = bias[n];
#pragma unroll
    for (int q = 0; q < G; ++q) v += part[q * N + n];
    if (RELU) v = fmaxf(v, 0.f);
    out[n] = v;
  }
  __syncthreads();
}

#define BLOCK_LN512(V, G, B, O)                                                 \
  {                                                                             \
    float s_ = (V), ss_ = (V) * (V);                                            \
    _Pragma("unroll")                                                           \
    for (int o_ = 32; o_ > 0; o_ >>= 1) {                                       \
      s_ += __shfl_xor(s_, o_); ss_ += __shfl_xor(ss_, o_);                     \
    }                                                                           \
    if ((tid & 63) == 0) { red[tid >> 6] = s_; red2[tid >> 6] = ss_; }          \
    __syncthreads();                                                            \
    s_ = 0.f; ss_ = 0.f;                                                        \
    _Pragma("unroll")                                                           \
    for (int w_ = 0; w_ < 8; ++w_) { s_ += red[w_]; ss_ += red2[w_]; }          \
    const float mean_ = s_ * (1.f / 512.f);                                     \
    const float inv_ = rsqrtf(ss_ * (1.f / 512.f) - mean_ * mean_ + 1e-5f);     \
    O = ((V) - mean_) * inv_ * (G)[tid] + (B)[tid];                             \
    __syncthreads();                                                            \
  }

__global__ __launch_bounds__(512)
void dec_layer(const float* __restrict__ tin,          // nullptr => ones
               const float* __restrict__ kvb, int kvstride,
               const bf16* __restrict__ WvT, const float* __restrict__ bv,
               const bf16* __restrict__ WpT, const float* __restrict__ bp,
               const float* __restrict__ g1, const float* __restrict__ b1,
               const bf16* __restrict__ WqT, const float* __restrict__ bq,
               const bf16* __restrict__ WcpT, const float* __restrict__ bcp,
               const float* __restrict__ g2, const float* __restrict__ b2,
               const bf16* __restrict__ W1T, const float* __restrict__ b1f,
               const bf16* __restrict__ W2T, const float* __restrict__ b2f,
               const float* __restrict__ g3, const float* __restrict__ b3,
               const float* __restrict__ gf, const float* __restrict__ bf_,
               int dofinal, float* __restrict__ tout,
               const bf16* __restrict__ Wo1T, const float* __restrict__ ob1,
               bf16* __restrict__ o1b)
{
  __shared__ float Ts[512], Bs[512], Cs[512], F1[1024], part[2048];
  __shared__ float Ps[4][104];
  __shared__ float red[8], red2[8];
  const int r = blockIdx.x, tid = threadIdx.x;
  Ts[tid] = tin ? tin[r * 512 + tid] : 1.0f;
  __syncthreads();

  gemvT<512, 512, 0>(tid, Ts, WvT, bv, Bs, part);
  gemvT<512, 512, 0>(tid, Bs, WpT, bp, Cs, part);
  {
    const float rr = Cs[tid] + Ts[tid];
    float o;
    BLOCK_LN512(rr, g1, b1, o)
    Ts[tid] = o;
  }
  __syncthreads();

  gemvT<512, 512, 0>(tid, Ts, WqT, bq, Bs, part);

  if (tid < 256) {
    const int h = tid >> 6, lane = tid & 63;
    const float scale = 0.08838834764831845f;
    const float* Qh = Bs + h * 128;
    float s0, s1 = -3e38f;
    {
      const float* kr = kvb + (size_t)(lane * 32 + r) * kvstride + h * 128;
      float a = 0.f;
#pragma unroll 16
      for (int d = 0; d < 128; ++d) a += Qh[d] * kr[d];
      s0 = a * scale;
    }
    if (lane + 64 < 100) {
      const float* kr = kvb + (size_t)((lane + 64) * 32 + r) * kvstride + h * 128;
      float a = 0.f;
#pragma unroll 16
      for (int d = 0; d < 128; ++d) a += Qh[d] * kr[d];
      s1 = a * scale;
    }
    float mx = fmaxf(s0, s1);
#pragma unroll
    for (int o = 32; o > 0; o >>= 1) mx = fmaxf(mx, __shfl_xor(mx, o));
    const float e0 = expf(s0 - mx);
    const float e1 = (lane + 64 < 100) ? expf(s1 - mx) : 0.f;
    float sm = e0 + e1;
#pragma unroll
    for (int o = 32; o > 0; o >>= 1) sm += __shfl_xor(sm, o);
    Ps[h][lane] = e0 / sm;
    if (lane + 64 < 100) Ps[h][lane + 64] = e1 / sm;
  }
  __syncthreads();
  if (tid < 256) {
    const int h = tid >> 6, lane = tid & 63;
#pragma unroll
    for (int u = 0; u < 2; ++u) {
      const int d = lane + u * 64;
      const float* vb = kvb + 512 + h * 128 + d;
      float a = 0.f;
      for (int k = 0; k < 100; ++k) a += Ps[h][k] * vb[(size_t)(k * 32 + r) * kvstride];
      Bs[h * 128 + d] = a;
    }
  }
  __syncthreads();

  gemvT<512, 512, 0>(tid, Bs, WcpT, bcp, Cs, part);
  {
    const float rr = Cs[tid] + Ts[tid];
    float o;
    BLOCK_LN512(rr, g2, b2, o)
    Ts[tid] = o;
  }
  __syncthreads();

  gemvT<1024, 512, 1>(tid, Ts, W1T, b1f, F1, part);
  gemvT<512, 1024, 0>(tid, F1, W2T, b2f, Cs, part);
  {
    const float rr = Cs[tid] + Ts[tid];
    float o;
    BLOCK_LN512(rr, g3, b3, o)
    if (dofinal) {
      float f;
      BLOCK_LN512(o, gf, bf_, f)
      o = f;
    }
    tout[r * 512 + tid] = o;
    if (dofinal) {
      Ts[tid] = o;
      __syncthreads();
      // fused out1: row r of C(32,2048) = relu(t @ Wo1T + b); 4 outputs/thread
      const short4v* wp = (const short4v*)Wo1T;   // [512][512 bf16-quads]
      float ax = 0.f, ay = 0.f, az = 0.f, aw = 0.f;
#pragma unroll 8
      for (int k = 0; k < 512; ++k) {
        const float s = Ts[k];
        union { short4v v; bf16 h[4]; } w;
        w.v = wp[(size_t)k * 512 + tid];
        ax += s * __bfloat162float(w.h[0]);
        ay += s * __bfloat162float(w.h[1]);
        az += s * __bfloat162float(w.h[2]);
        aw += s * __bfloat162float(w.h[3]);
      }
      union { short4v v; bf16 h[4]; } u;
      u.h[0] = __float2bfloat16(fmaxf(ax + ob1[4 * tid], 0.f));
      u.h[1] = __float2bfloat16(fmaxf(ay + ob1[4 * tid + 1], 0.f));
      u.h[2] = __float2bfloat16(fmaxf(az + ob1[4 * tid + 2], 0.f));
      u.h[3] = __float2bfloat16(fmaxf(aw + ob1[4 * tid + 3], 0.f));
      *(short4v*)(o1b + (size_t)r * 2048 + 4 * tid) = u.v;
      const short4v z = {0, 0, 0, 0};
#pragma unroll
      for (int rr = r + 32; rr < 128; rr += 32)
        *(short4v*)(o1b + (size_t)rr * 2048 + 4 * tid) = z;
    }
  }
}

// ---------------------------------------------------------------------------
// out3 split-K reduce (8 slices, +bias(+guard)+relu) fused with pool. grid 32.
__global__ __launch_bounds__(256)
void reduce_pool(const float* __restrict__ P, size_t pstride,
                 const float* __restrict__ bias, float* __restrict__ out)
{
  __shared__ float row[NOUT3];
  const int b = blockIdx.x, t = threadIdx.x;
  for (int n = t * 4; n < NOUT3; n += 1024) {
    const size_t o = (size_t)b * NOUT3 + n;
    float4 s = *(const float4*)(P + o);
#pragma unroll
    for (int k = 1; k < 8; ++k) {
      const float4 p = *(const float4*)(P + (size_t)k * pstride + o);
      s.x += p.x; s.y += p.y; s.z += p.z; s.w += p.w;
    }
    row[n]     = fmaxf(s.x + ((n     < FLATIN) ? bias[n]     : 0.f), 0.f);
    row[n + 1] = fmaxf(s.y + ((n + 1 < FLATIN) ? bias[n + 1] : 0.f), 0.f);
    row[n + 2] = fmaxf(s.z + ((n + 2 < FLATIN) ? bias[n + 2] : 0.f), 0.f);
    row[n + 3] = fmaxf(s.w + ((n + 3 < FLATIN) ? bias[n + 3] : 0.f), 0.f);
  }
  __syncthreads();
  for (int i = t; i < 135 * 103; i += 256) {
    const int j = i % 103, r = i / 103;
    const int rs = (r * 143) / 135, re = ((r + 1) * 143 + 134) / 135;
    const int cs = (j * 111) / 103, ce = ((j + 1) * 111 + 102) / 103;
    float s = 0.f;
    for (int rr = rs; rr < re; ++rr)
      for (int cc = cs; cc < ce; ++cc)
        s += row[rr * 111 + cc];
    out[(size_t)b * (135 * 103) + i] = s / (float)((re - rs) * (ce - cs));
  }
}

// ---------------------------------------------------------------------------
extern "C" void kernel_launch(void* const* d_in, const int* in_sizes, int n_in,
                              void* d_out, int out_size, void* d_ws, size_t ws_size,
                              hipStream_t stream)
{
  (void)in_sizes; (void)n_in; (void)out_size; (void)ws_size;

  const float* x          = (const float*)d_in[0];
  const float* fc1_w      = (const float*)d_in[1];
  const float* fc1_b      = (const float*)d_in[2];
  const float* fc2_w      = (const float*)d_in[3];
  const float* fc2_b      = (const float*)d_in[4];
  const float* fc3_w      = (const float*)d_in[5];
  const float* fc3_b      = (const float*)d_in[6];
  const float* out1_w     = (const float*)d_in[7];
  const float* out1_b     = (const float*)d_in[8];
  const float* out2_w     = (const float*)d_in[9];
  const float* out2_b     = (const float*)d_in[10];
  const float* out3_w     = (const float*)d_in[11];
  const float* out3_b     = (const float*)d_in[12];
  const float* enc_qkv_w  = (const float*)d_in[13];
  const float* enc_qkv_b  = (const float*)d_in[14];
  const float* enc_proj_w = (const float*)d_in[15];
  const float* enc_proj_b = (const float*)d_in[16];
  const float* enc_ff1_w  = (const float*)d_in[17];
  const float* enc_ff1_b  = (const float*)d_in[18];
  const float* enc_ff2_w  = (const float*)d_in[19];
  const float* enc_ff2_b  = (const float*)d_in[20];
  const float* enc_ln1_g  = (const float*)d_in[21];
  const float* enc_ln1_b  = (const float*)d_in[22];
  const float* enc_ln2_g  = (const float*)d_in[23];
  const float* enc_ln2_b  = (const float*)d_in[24];
  const float* enc_lnf_g  = (const float*)d_in[25];
  const float* enc_lnf_b  = (const float*)d_in[26];
  const float* dec_sa_qkv_w  = (const float*)d_in[27];
  const float* dec_sa_qkv_b  = (const float*)d_in[28];
  const float* dec_sa_proj_w = (const float*)d_in[29];
  const float* dec_sa_proj_b = (const float*)d_in[30];
  const float* dec_ca_qkv_w  = (const float*)d_in[31];
  const float* dec_ca_qkv_b  = (const float*)d_in[32];
  const float* dec_ca_proj_w = (const float*)d_in[33];
  const float* dec_ca_proj_b = (const float*)d_in[34];
  const float* dec_ff1_w  = (const float*)d_in[35];
  const float* dec_ff1_b  = (const float*)d_in[36];
  const float* dec_ff2_w  = (const float*)d_in[37];
  const float* dec_ff2_b  = (const float*)d_in[38];
  const float* dec_ln1_g  = (const float*)d_in[39];
  const float* dec_ln1_b  = (const float*)d_in[40];
  const float* dec_ln2_g  = (const float*)d_in[41];
  const float* dec_ln2_b  = (const float*)d_in[42];
  const float* dec_ln3_g  = (const float*)d_in[43];
  const float* dec_ln3_b  = (const float*)d_in[44];
  const float* dec_lnf_g  = (const float*)d_in[45];
  const float* dec_lnf_b  = (const float*)d_in[46];

  char* wsp = (char*)d_ws;
  size_t off = 0;
  auto alloc = [&](size_t nbytes) -> char* {
    char* p = wsp + off;
    off += (nbytes + 255) & ~(size_t)255;
    return p;
  };

  bf16* xb     = (bf16*)alloc((size_t)MPAD * KPAD1 * 2);
  bf16* Wb1    = (bf16*)alloc((size_t)4096 * KPAD1 * 2);
  bf16* Wb2    = (bf16*)alloc((size_t)2048 * 4096 * 2);
  bf16* Wb3    = (bf16*)alloc((size_t)512 * 2048 * 2);
  bf16* Wqkvb  = (bf16*)alloc((size_t)2 * 1536 * 512 * 2);
  bf16* Wprojb = (bf16*)alloc((size_t)2 * 512 * 512 * 2);
  bf16* Wff1b  = (bf16*)alloc((size_t)2 * 1024 * 512 * 2);
  bf16* Wff2b  = (bf16*)alloc((size_t)2 * 512 * 1024 * 2);
  bf16* Wkv2b  = (bf16*)alloc((size_t)2048 * 512 * 2);
  int*   nz      = (int*)alloc(ROWS * 4);
  int*   padmask = (int*)alloc(ROWS * 4);
  int*   idx     = (int*)alloc(MPAD * 4);
  int*   pos     = (int*)alloc(ROWS * 4);
  int*   cnt     = (int*)alloc(256);
  float* kvbias  = (float*)alloc(2048 * 4);
  bf16* h1c = (bf16*)alloc((size_t)MPAD * 4096 * 2);
  bf16* h2c = (bf16*)alloc((size_t)MPAD * 2048 * 2);
  float* hf  = (float*)alloc((size_t)ROWS * 512 * 4);
  bf16* hb = (bf16*)alloc((size_t)ROWS * 512 * 2);
  float* qkvbuf = (float*)alloc((size_t)ROWS * 1536 * 4);
  bf16* attnb = (bf16*)alloc((size_t)ROWS * 512 * 2);
  float* pjf  = (float*)alloc((size_t)ROWS * 512 * 4);
  bf16* f1b = (bf16*)alloc((size_t)ROWS * 1024 * 2);
  float* f2f  = (float*)alloc((size_t)ROWS * 512 * 4);
  bf16* memb = (bf16*)alloc((size_t)ROWS * 512 * 2);
  float* kv01 = (float*)alloc((size_t)ROWS * 2048 * 4);
  float* tbuf = (float*)alloc(32 * 512 * 4);
  // bf16 transposed weights (decoder + out1)
  bf16* WvT[2]  = { (bf16*)alloc(512 * 512 * 2), (bf16*)alloc(512 * 512 * 2) };
  bf16* WpT[2]  = { (bf16*)alloc(512 * 512 * 2), (bf16*)alloc(512 * 512 * 2) };
  bf16* WqT[2]  = { (bf16*)alloc(512 * 512 * 2), (bf16*)alloc(512 * 512 * 2) };
  bf16* WcpT[2] = { (bf16*)alloc(512 * 512 * 2), (bf16*)alloc(512 * 512 * 2) };
  bf16* W1T[2]  = { (bf16*)alloc(512 * 1024 * 2), (bf16*)alloc(512 * 1024 * 2) };
  bf16* W2T[2]  = { (bf16*)alloc(1024 * 512 * 2), (bf16*)alloc(1024 * 512 * 2) };
  bf16* Wo1T    = (bf16*)alloc((size_t)512 * 2048 * 2);
  float* fcP  = (float*)alloc((size_t)4 * MPAD * 4096 * 4);   // 218 MB
  float* encP = (float*)alloc((size_t)2 * ROWS * 1536 * 4);   // aliases

  float* outP = fcP;                                           // <=66 MB
  bf16* o1b  = (bf16*)((char*)encP + ((size_t)20 << 20));
  bf16* o2b  = (bf16*)((char*)encP + ((size_t)22 << 20));

  const size_t psF1 = (size_t)MPAD * 4096;
  const size_t psF2 = (size_t)MPAD * 2048;
  const size_t psF3 = (size_t)MPAD * 512;

  // ---- phase 0: merged prep (conv_x | cvt | fc1 cvt | transpose), compact --
  {
    PrepArgs pa;
    pa.x = x; pa.xb = xb; pa.nz = nz; pa.nConv = ROWS + 1;
    const float* srcs[8] = { enc_qkv_w, enc_proj_w, enc_ff1_w, enc_ff2_w,
                             dec_ca_qkv_w + (size_t)512 * 512,
                             dec_ca_qkv_w + (size_t)(1536 + 512) * 512,
                             fc2_w, fc3_w };
    bf16* dsts[8] = { Wqkvb, Wprojb, Wff1b, Wff2b,
                      Wkv2b, Wkv2b + (size_t)1024 * 512, Wb2, Wb3 };
    const int counts[8] = { 2*1536*512, 2*512*512, 2*1024*512, 2*512*1024,
                            1024*512, 1024*512, 2048*4096, 512*2048 };
    int c = 0;
    for (int i = 0; i < 8; ++i) { pa.cv.src[i] = srcs[i]; pa.cv.dst[i] = dsts[i];
                                  pa.cv.cum[i] = c; c += counts[i] >> 11; }
    pa.nCvt = c;
    pa.fc1w = fc1_w; pa.wb1 = Wb1; pa.nFc1 = 4096;
    const float* tsr[13];
    bf16* tds[13];
    int R[13], C[13];
    int n = 0;
    for (int L = 0; L < 2; ++L) {
      tsr[n] = dec_sa_qkv_w + (size_t)L * 1536 * 512 + (size_t)1024 * 512;
      tds[n] = WvT[L]; R[n] = 512; C[n] = 512; ++n;
      tsr[n] = dec_sa_proj_w + (size_t)L * 512 * 512;
      tds[n] = WpT[L]; R[n] = 512; C[n] = 512; ++n;
      tsr[n] = dec_ca_qkv_w + (size_t)L * 1536 * 512;
      tds[n] = WqT[L]; R[n] = 512; C[n] = 512; ++n;
      tsr[n] = dec_ca_proj_w + (size_t)L * 512 * 512;
      tds[n] = WcpT[L]; R[n] = 512; C[n] = 512; ++n;
      tsr[n] = dec_ff1_w + (size_t)L * 1024 * 512;
      tds[n] = W1T[L]; R[n] = 1024; C[n] = 512; ++n;
      tsr[n] = dec_ff2_w + (size_t)L * 512 * 1024;
      tds[n] = W2T[L]; R[n] = 512; C[n] = 1024; ++n;
    }
    tsr[n] = out1_w; tds[n] = Wo1T; R[n] = 2048; C[n] = 512; ++n;
    int tc = 0;
    for (int i = 0; i < 13; ++i) {
      pa.tr.src[i] = tsr[i]; pa.tr.dst[i] = tds[i];
      pa.tr.R[i] = R[i]; pa.tr.C[i] = C[i];
      pa.tr.cum[i] = tc; tc += (R[i] >> 6) * (C[i] >> 6);
    }
    prep_kernel<<<pa.nConv + pa.nCvt + pa.nFc1 + tc, 256, 0, stream>>>(pa);
  }
  compact_kernel<<<1, 256, 0, stream>>>(nz, idx, pos, cnt, padmask,
                                        dec_ca_qkv_b, kvbias);

  // ---- phase 1: input MLP (split-K) ----
  gemm_bf16<1><<<26 * 32 * 2, 256, 0, stream>>>(xb, Wb1, idx, cnt, fcP,
      KPAD1, 4096, 26, 2, psF1);
  reduce_kernel<1, 0, 1><<<dim3(4, MPAD), 256, 0, stream>>>(fcP, psF1, 2,
      fc1_b, nullptr, h1c, 4096, cnt);
  gemm_bf16<0><<<26 * 16 * 4, 256, 0, stream>>>(h1c, Wb2, nullptr, cnt, fcP,
      4096, 2048, 26, 4, psF2);
  reduce_kernel<1, 0, 1><<<dim3(2, MPAD), 256, 0, stream>>>(fcP, psF2, 4,
      fc2_b, nullptr, h2c, 2048, cnt);
  gemm_bf16<0><<<26 * 4 * 4, 256, 0, stream>>>(h2c, Wb3, nullptr, cnt, fcP,
      2048, 512, 26, 4, psF3);
  scatter_pe_reduce<<<ROWS, 256, 0, stream>>>(fcP, psF3, 4, pos, fc3_b, hf, hb);

  // ---- phase 2: encoder ----
  for (int L = 0; L < 2; ++L) {
    gemm_direct<0, 1, 0><<<25 * 12, 256, 0, stream>>>(hb, Wqkvb + (size_t)L * 1536 * 512,
        enc_qkv_b + L * 1536, qkvbuf, nullptr, 512, 1536, 25);
    enc_attn_kernel<<<dim3(128, 13), 256, 0, stream>>>(qkvbuf, padmask, attnb);
    gemm_direct<0, 1, 0><<<25 * 4, 256, 0, stream>>>(attnb, Wprojb + (size_t)L * 512 * 512,
        enc_proj_b + L * 512, pjf, nullptr, 512, 512, 25);
    ln_kernel<<<ROWS, 256, 0, stream>>>(hf, pjf, enc_ln1_g + L * 512, enc_ln1_b + L * 512,
        nullptr, nullptr, 0, hf, hb);
    gemm_direct<1, 0, 1><<<25 * 8, 256, 0, stream>>>(hb, Wff1b + (size_t)L * 1024 * 512,
        enc_ff1_b + L * 1024, nullptr, f1b, 512, 1024, 25);
    gemm_direct<0, 1, 0><<<25 * 4, 256, 0, stream>>>(f1b, Wff2b + (size_t)L * 512 * 1024,
        enc_ff2_b + L * 512, f2f, nullptr, 1024, 512, 25);
    if (L == 0) {
      ln_kernel<<<ROWS, 256, 0, stream>>>(hf, f2f, enc_ln2_g, enc_ln2_b,
          nullptr, nullptr, 0, hf, hb);
    } else {
      ln_kernel<<<ROWS, 256, 0, stream>>>(hf, f2f, enc_ln2_g + 512, enc_ln2_b + 512,
          enc_lnf_g, enc_lnf_b, 1, nullptr, memb);
    }
  }

  // ---- decoder KV (both layers, one GEMM) ----
  gemm_direct<0, 1, 0><<<25 * 16, 256, 0, stream>>>(memb, Wkv2b, kvbias,
      kv01, nullptr, 512, 2048, 25);

  // ---- phase 3: fused decoder layers (bf16 weights; out1 fused into L1) ----
  for (int L = 0; L < 2; ++L) {
    dec_layer<<<32, 512, 0, stream>>>(
        (L == 0) ? nullptr : tbuf,
        kv01 + (size_t)L * 1024, 2048,
        WvT[L], dec_sa_qkv_b + L * 1536 + 1024,
        WpT[L], dec_sa_proj_b + L * 512,
        dec_ln1_g + L * 512, dec_ln1_b + L * 512,
        WqT[L], dec_ca_qkv_b + L * 1536,
        WcpT[L], dec_ca_proj_b + L * 512,
        dec_ln2_g + L * 512, dec_ln2_b + L * 512,
        W1T[L], dec_ff1_b + L * 1024,
        W2T[L], dec_ff2_b + L * 512,
        dec_ln3_g + L * 512, dec_ln3_b + L * 512,
        dec_lnf_g, dec_lnf_b, (L == 1) ? 1 : 0, tbuf,
        Wo1T, out1_b, o1b);
  }

  // ---- phase 4: output MLP (fp32-weight GEMMs, conversion fused) ----
  gemm_w32<<<32 * 16, 256, 0, stream>>>(o1b, out2_w, outP,
      2048, 4096, 16, (size_t)128 * 4096, 4096);
  reduce_kernel<1, 0, 1><<<dim3(4, 128), 256, 0, stream>>>(outP, (size_t)128 * 4096, 16,
      out2_b, nullptr, o2b, 4096, nullptr);
  gemm_w32<<<125 * 8, 256, 0, stream>>>(o2b, out3_w, outP,
      4096, NOUT3, 8, (size_t)128 * NOUT3, FLATIN);
  reduce_pool<<<32, 256, 0, stream>>>(outP, (size_t)128 * NOUT3, out3_b, (float*)d_out);
}